// Round 12
// baseline (353.787 us; speedup 1.0000x reference)
//
#include <hip/hip_runtime.h>
#include <hip/hip_bf16.h>
#include <math.h>

// ---------------- constants ----------------
#define NP 512
#define NIMG 256
#define NDEL 32
#define NTH 240
#define NINT 250
#define SOS_ELEMS (512*512)
#define MLP_P 32
// swizzled physical index for FFT LDS rows (padded variant, 576/row)
#define PHY(i) ((i) + ((i) >> 3))
#define RSW 576   // PHY(511)=574 -> row array size
// XOR-swizzle for the UNPADDED 512/row variant (k_colfft_part 32KB diet):
// bijective on [0,512): bits 3..8 preserved, bits 0..2 ^= bits 6..8.
#define SWZ(i) ((i) ^ (((i) >> 6) & 7))
#define PI_F 3.14159265358979323846f

__device__ __forceinline__ int brev9(int i) { return (int)(__brev((unsigned)i) >> 23); }

__device__ __forceinline__ float block_reduce_any(float v) {
  #pragma unroll
  for (int o = 32; o > 0; o >>= 1) v += __shfl_down(v, o, 64);
  __shared__ float red[16];
  int lane = threadIdx.x & 63, wid = threadIdx.x >> 6;
  __syncthreads();
  if (lane == 0) red[wid] = v;
  __syncthreads();
  float r = 0.f;
  if (threadIdx.x == 0) {
    int nw = blockDim.x >> 6;
    for (int i = 0; i < nw; ++i) r += red[i];
  }
  return r;
}

// block reduce using caller-provided LDS scratch (>=4 floats) — for kernels
// whose LDS budget is exact (no room for a static red[]). 256-thread blocks.
__device__ __forceinline__ float block_reduce_scratch(float v, float* scratch) {
  #pragma unroll
  for (int o = 32; o > 0; o >>= 1) v += __shfl_down(v, o, 64);
  int lane = threadIdx.x & 63, wid = threadIdx.x >> 6;
  __syncthreads();
  if (lane == 0) scratch[wid] = v;
  __syncthreads();
  float r = 0.f;
  if (threadIdx.x == 0) {
    #pragma unroll
    for (int i = 0; i < 4; ++i) r += scratch[i];
  }
  return r;
}

// ---- radix-4 FFT core butterfly (sign = -1 fwd, +1 inv) ----
__device__ __forceinline__ void r4_bfly(float2& x0, float2& x1, float2& x2, float2& x3,
                                        float c1, float s1n, float c2, float s2n, float sign) {
  float t1x = x1.x * c1 - x1.y * s1n, t1y = x1.x * s1n + x1.y * c1;
  float y0x = x0.x + t1x, y0y = x0.y + t1y;
  float y1x = x0.x - t1x, y1y = x0.y - t1y;
  float t3x = x3.x * c1 - x3.y * s1n, t3y = x3.x * s1n + x3.y * c1;
  float y2x = x2.x + t3x, y2y = x2.y + t3y;
  float y3x = x2.x - t3x, y3y = x2.y - t3y;
  float t2x = y2x * c2 - y2y * s2n, t2y = y2x * s2n + y2y * c2;
  float ux = y3x * c2 - y3y * s2n, uy = y3x * s2n + y3y * c2;
  float t4x = -sign * uy, t4y = sign * ux;   // rotate by sign*i (fwd: -i)
  x0 = make_float2(y0x + t2x, y0y + t2y);
  x2 = make_float2(y0x - t2x, y0y - t2y);
  x1 = make_float2(y1x + t4x, y1y + t4y);
  x3 = make_float2(y1x - t4x, y1y - t4y);
}

// radix-4 FFT, 512 pts x 8 rows, 256 threads, XOR-swizzled UNPADDED rows.
__device__ __forceinline__ void fft512_r4_fwd_rows_swz(float2 (*s)[512], int lt) {
  #pragma unroll
  for (int pass = 0; pass < 4; ++pass) {
    const int sh = 2 * pass;
    const int h = 1 << sh;
    int p = lt & 127;
    int rbase = (lt >> 7) << 2;
    int j = p & (h - 1);
    int g = p >> sh;
    int base = (g << (sh + 2)) + j;
    int i0 = SWZ(base), i1 = SWZ(base + h), i2 = SWZ(base + 2 * h), i3 = SWZ(base + 3 * h);
    float ang1 = -PI_F * (float)j / (float)h;
    float s1n, c1; __sincosf(ang1, &s1n, &c1);
    float s2n, c2; __sincosf(0.5f * ang1, &s2n, &c2);
    #pragma unroll
    for (int rr = 0; rr < 4; ++rr) {
      int r = rbase + rr;
      float2 x0 = s[r][i0], x1 = s[r][i1], x2 = s[r][i2], x3 = s[r][i3];
      r4_bfly(x0, x1, x2, x3, c1, s1n, c2, s2n, -1.f);
      s[r][i0] = x0; s[r][i1] = x1; s[r][i2] = x2; s[r][i3] = x3;
    }
    __syncthreads();
  }
  {
    int p = lt;
    int i1 = SWZ(p), i2 = SWZ(p + 256);
    float ang = -PI_F * (float)p * (1.f / 256.f);
    float sn, cs; __sincosf(ang, &sn, &cs);
    #pragma unroll
    for (int r = 0; r < 8; ++r) {
      float2 a = s[r][i1], b = s[r][i2];
      float tr = b.x * cs - b.y * sn;
      float ti = b.x * sn + b.y * cs;
      s[r][i1] = make_float2(a.x + tr, a.y + ti);
      s[r][i2] = make_float2(a.x - tr, a.y - ti);
    }
    __syncthreads();
  }
}

// radix-4 FFT, 512 pts x 4 rows (packed real pairs), 256 threads, padded.
__device__ __forceinline__ void fft512_r4_fwd_rows4(float2 (*s)[RSW], int tid) {
  #pragma unroll
  for (int pass = 0; pass < 4; ++pass) {
    const int sh = 2 * pass;
    const int h = 1 << sh;
    int p = tid & 127;
    int rbase = (tid >> 7) << 1;
    int j = p & (h - 1);
    int g = p >> sh;
    int base = (g << (sh + 2)) + j;
    int i0 = PHY(base), i1 = PHY(base + h), i2 = PHY(base + 2 * h), i3 = PHY(base + 3 * h);
    float ang1 = -PI_F * (float)j / (float)h;
    float s1n, c1; __sincosf(ang1, &s1n, &c1);
    float s2n, c2; __sincosf(0.5f * ang1, &s2n, &c2);
    #pragma unroll
    for (int rr = 0; rr < 2; ++rr) {
      int r = rbase + rr;
      float2 x0 = s[r][i0], x1 = s[r][i1], x2 = s[r][i2], x3 = s[r][i3];
      r4_bfly(x0, x1, x2, x3, c1, s1n, c2, s2n, -1.f);
      s[r][i0] = x0; s[r][i1] = x1; s[r][i2] = x2; s[r][i3] = x3;
    }
    __syncthreads();
  }
  {
    int p = tid;
    int i1 = PHY(p), i2 = PHY(p + 256);
    float ang = -PI_F * (float)p * (1.f / 256.f);
    float sn, cs; __sincosf(ang, &sn, &cs);
    #pragma unroll
    for (int r = 0; r < 4; ++r) {
      float2 a = s[r][i1], b = s[r][i2];
      float tr = b.x * cs - b.y * sn;
      float ti = b.x * sn + b.y * cs;
      s[r][i1] = make_float2(a.x + tr, a.y + ti);
      s[r][i2] = make_float2(a.x - tr, a.y - ti);
    }
    __syncthreads();
  }
}

// radix-4 FFT, single 512-pt row, 256 threads, padded, sign-param.
// Generic float2* so it can run inside a larger LDS region.
__device__ __forceinline__ void fft512_r4_row(float2* s, int tid, float sign) {
  #pragma unroll
  for (int pass = 0; pass < 4; ++pass) {
    const int sh = 2 * pass;
    const int h = 1 << sh;
    if (tid < 128) {
      int j = tid & (h - 1);
      int g = tid >> sh;
      int base = (g << (sh + 2)) + j;
      int i0 = PHY(base), i1 = PHY(base + h), i2 = PHY(base + 2 * h), i3 = PHY(base + 3 * h);
      float ang1 = sign * PI_F * (float)j / (float)h;
      float s1n, c1; __sincosf(ang1, &s1n, &c1);
      float s2n, c2; __sincosf(0.5f * ang1, &s2n, &c2);
      float2 x0 = s[i0], x1 = s[i1], x2 = s[i2], x3 = s[i3];
      r4_bfly(x0, x1, x2, x3, c1, s1n, c2, s2n, sign);
      s[i0] = x0; s[i1] = x1; s[i2] = x2; s[i3] = x3;
    }
    __syncthreads();
  }
  {
    int i1 = PHY(tid), i2 = PHY(tid + 256);
    float ang = sign * PI_F * (float)tid * (1.f / 256.f);
    float sn, cs; __sincosf(ang, &sn, &cs);
    float2 a = s[i1], b = s[i2];
    float tr = b.x * cs - b.y * sn;
    float ti = b.x * sn + b.y * cs;
    s[i1] = make_float2(a.x + tr, a.y + ti);
    s[i2] = make_float2(a.x - tr, a.y - ti);
    __syncthreads();
  }
}

// acc layout in workspace (floats): 3 quantity groups x 16 slots x 16-float
// (64B) stride — atomics spread over 16 cache lines per group (R9 lesson:
// same-line atomics serialize ~10ns each at the coherent point).
#define ACC_G(g, slot) ((g) * 256 + ((slot) & 15) * 16)

// ---------------- K_front: FUSED {2x MLP tile | fwdT} -----------------------
// R3-verified. DO NOT retile the 128-thread MLP schedule (R10/R11/R15 of the
// prior session regressed — incl. 16-row wbuf); DO NOT spread the sos fill
// into fwdT blocks (R7 regressed); NO cooperative launch (R4-R6).
__global__ __launch_bounds__(256) void k_front(
    const float* __restrict__ W1, const float* __restrict__ b1,
    const float* __restrict__ W2, const float* __restrict__ b2,
    const float* __restrict__ W3, const float* __restrict__ b3,
    const float* __restrict__ W4v, const float* __restrict__ b4,
    const float* __restrict__ mgrid, const int* __restrict__ mask_idx,
    const float* __restrict__ mask, int M, int nMlpB,
    float* __restrict__ sos, float* __restrict__ acc,
    const float* __restrict__ y_img, float2* __restrict__ bufA) {
  __shared__ char raw[43008];   // MLP: 33792 hbuf + 8448 wbuf + 512 xy = 42752; fwdT: 18432
  int bid = blockIdx.x;
  int tid = threadIdx.x;
  if (bid < nMlpB) {
    // ================= two MLP tiles (64 points) =================
    float (*hbuf)[MLP_P][132] = (float (*)[MLP_P][132])raw;          // [2][32][132]
    float (*wbuf)[8][132]     = (float (*)[8][132])(raw + 33792);    // [2][8][132]
    float (*xy2)[2]           = (float (*)[2])(raw + 33792 + 8448);  // [64][2]
    int half = tid >> 7, lt = tid & 127;
    int base = bid * (2 * MLP_P) + half * MLP_P;
    if (lt < MLP_P * 2) {
      int p = lt >> 1, c = lt & 1;
      float v = 0.f;
      if (base + p < M) v = mgrid[(base + p) * 2 + c];
      xy2[half * MLP_P + p][c] = v;
    }
    if (bid == 0) {
      // zero acc (768 floats) + cnt (257 uints at float offset 768..1025)
      for (int e = tid; e < 1026; e += 256) acc[e] = 0.f;
    }
    for (int slab = bid; slab < 1024; slab += nMlpB) {
      int t = slab * 256 + tid;
      if (mask[t] == 0.f) sos[t] = 1499.363f;
    }
    __syncthreads();
    for (int e = lt; e < MLP_P * 128; e += 128) {
      int p = e >> 7, j = e & 127;
      hbuf[half][p][j] = __sinf(30.f * (xy2[half * MLP_P + p][0] * W1[j] +
                                        xy2[half * MLP_P + p][1] * W1[128 + j] + b1[j]));
    }
    __syncthreads();

    int jg = lt & 15, pg = lt >> 4;
    int jA = jg * 4, jB = 64 + jg * 4;
    int p0 = pg * 4;
    int wr = tid >> 4, wc = (tid & 15) << 3;   // wbuf writer coords, valid for tid<128
    #pragma unroll
    for (int layer = 0; layer < 2; ++layer) {
      const float* Wg = layer ? W3 : W2;
      const float* bb = layer ? b3 : b2;
      float acr[4][8];
      #pragma unroll
      for (int i = 0; i < 4; ++i)
        #pragma unroll
        for (int j = 0; j < 8; ++j) acr[i][j] = 0.f;

      float4 pre1, pre2;
      if (tid < 128) {
        pre1 = *(const float4*)&Wg[wr * 128 + wc];
        pre2 = *(const float4*)&Wg[wr * 128 + wc + 4];
      }
      for (int c = 0; c < 16; ++c) {
        if (tid < 128) {
          *(float4*)&wbuf[c & 1][wr][wc] = pre1;
          *(float4*)&wbuf[c & 1][wr][wc + 4] = pre2;
        }
        __syncthreads();
        if (tid < 128 && c < 15) {
          pre1 = *(const float4*)&Wg[((c + 1) * 8 + wr) * 128 + wc];
          pre2 = *(const float4*)&Wg[((c + 1) * 8 + wr) * 128 + wc + 4];
        }
        int k0 = c * 8;
        float hreg[4][8];
        #pragma unroll
        for (int i = 0; i < 4; ++i) {
          float4 ha = *(const float4*)&hbuf[half][p0 + i][k0];
          float4 hb = *(const float4*)&hbuf[half][p0 + i][k0 + 4];
          hreg[i][0] = ha.x; hreg[i][1] = ha.y; hreg[i][2] = ha.z; hreg[i][3] = ha.w;
          hreg[i][4] = hb.x; hreg[i][5] = hb.y; hreg[i][6] = hb.z; hreg[i][7] = hb.w;
        }
        #pragma unroll
        for (int kk = 0; kk < 8; ++kk) {
          float4 wa = *(const float4*)&wbuf[c & 1][kk][jA];
          float4 wb = *(const float4*)&wbuf[c & 1][kk][jB];
          float w8[8] = {wa.x, wa.y, wa.z, wa.w, wb.x, wb.y, wb.z, wb.w};
          #pragma unroll
          for (int i = 0; i < 4; ++i) {
            float hv = hreg[i][kk];
            #pragma unroll
            for (int j = 0; j < 8; ++j) acr[i][j] += hv * w8[j];
          }
        }
      }
      float breg[8];
      #pragma unroll
      for (int j = 0; j < 4; ++j) { breg[j] = bb[jA + j]; breg[4 + j] = bb[jB + j]; }
      __syncthreads();
      #pragma unroll
      for (int i = 0; i < 4; ++i) {
        float o[8];
        #pragma unroll
        for (int j = 0; j < 8; ++j) o[j] = __sinf(30.f * (acr[i][j] + breg[j]));
        *(float4*)&hbuf[half][p0 + i][jA] = make_float4(o[0], o[1], o[2], o[3]);
        *(float4*)&hbuf[half][p0 + i][jB] = make_float4(o[4], o[5], o[6], o[7]);
      }
      __syncthreads();
    }
    {
      int p = lt >> 2, q = lt & 3;
      float s = 0.f;
      #pragma unroll
      for (int k = 0; k < 32; k += 4) {
        float4 h4 = *(const float4*)&hbuf[half][p][q * 32 + k];
        float4 w4 = *(const float4*)&W4v[q * 32 + k];
        s += h4.x * w4.x + h4.y * w4.y + h4.z * w4.z + h4.w * w4.w;
      }
      s += __shfl_down(s, 1, 64);
      s += __shfl_down(s, 2, 64);
      if (q == 0 && base + p < M)
        sos[mask_idx[base + p]] = (s + b4[0]) * 170.f + 1550.f;
    }
  } else {
    // ================= fwdT: real-pair packed v-axis FFT, Hermitian store ====
    float2 (*s)[RSW] = (float2 (*)[RSW])raw;   // [4][RSW]
    int fb = bid - nMlpB;
    int rt = fb & 31;
    int d = fb >> 5;
    const float INV2S2 = (float)(0.6931471805599453 / 1406.25);
    for (int e = tid; e < 2048; e += 256) {
      int i = e >> 8, c = e & 255;
      int r = rt * 8 + i;
      float axr = (float)r - 127.5f;
      float axc = (float)c - 127.5f;
      float g = __expf(-(axr * axr + axc * axc) * INV2S2);
      float val = y_img[((size_t)d << 16) + (r << 8) + c] * g;
      int p = i >> 1, comp = i & 1;
      ((float*)&s[p][PHY(brev9((c + 384) & 511))])[comp] = val;
      ((float*)&s[p][PHY(brev9(c + 128))])[comp] = 0.f;
    }
    __syncthreads();
    fft512_r4_fwd_rows4(s, tid);
    float2* outp = bufA + ((size_t)d << 17) + rt * 8;
    for (int e = tid; e < 2056; e += 256) {
      int i = e & 7, v = e >> 3;
      int p = i >> 1, comp = i & 1;
      float2 Zv = s[p][PHY(v)];
      float2 Zm = s[p][PHY((512 - v) & 511)];
      float2 Yv;
      if (comp == 0) Yv = make_float2(0.5f * (Zv.x + Zm.x), 0.5f * (Zv.y - Zm.y));
      else           Yv = make_float2(0.5f * (Zv.y + Zm.y), 0.5f * (Zm.x - Zv.x));
      outp[(size_t)v * 256 + i] = Yv;
    }
  }
}

// ---------------- K_side: wavefront only ----------------
__global__ __launch_bounds__(256) void k_side(
    const float* __restrict__ sos, const float* __restrict__ xq_p,
    const float* __restrict__ yq_p, const float* __restrict__ x_vec,
    const float* __restrict__ y_vec, float* __restrict__ wfs) {
  int i = blockIdx.x;
  int j = threadIdx.x;
  float xq = xq_p[0], yq = yq_p[0];
  float r = sqrtf(xq * xq + yq * yq);
  float phi = atan2f(xq, yq);
  float th = (float)((double)i * (2.0 * M_PI / 239.0));
  float sn = sinf(th - phi), cd = cosf(th - phi);
  const float R2 = 0.008f * 0.008f;
  float disc = fmaxf(R2 - (r * sn) * (r * sn), 0.f);
  float sq = sqrtf(disc);
  float l_in = sq + r * cd;
  float l_out = 2.f * sq * (cd >= 0.f ? 1.f : 0.f);
  float l = (r < 0.008f) ? l_in : l_out;
  float x0 = x_vec[0], dx = x_vec[1] - x_vec[0];
  float y0 = y_vec[0], dy = y_vec[1] - y_vec[0];
  float sinth = sinf(th), costh = cosf(th);
  float contrib = 0.f;
  if (j < NINT) {
    float sj = (float)j * (1.f / 249.f);
    int xi = (int)rintf((xq - l * sj * sinth - x0) / dx);
    int yi = (int)rintf((yq - l * sj * costh - y0) / dy);
    float sv = sos[(((-yi) & 511) << 9) + (xi & 511)];
    float f = 1.f - 1500.f / sv;
    float wgt = (j == 0 || j == NINT - 1) ? 0.5f : 1.f;
    contrib = wgt * f;
  }
  float tot = block_reduce_any(contrib);
  if (threadIdx.x == 0) wfs[i] = tot * l * (1.f / 249.f);
}

// ---------------- K3: part + FUSED fin (last-arriver reduction) -------------
// R10 geometry (32KB LDS, 5 blocks/CU, single round) + R11: the 4th block to
// finish a v's partials does fin's work for that v inline (combine -> X ->
// loss -> u-IFFT -> transposed+mirrored Xo store). Sync = device-scope
// release (per-thread threadfence + barrier, then ONE atomicAdd on cnt[v])
// then acquire fence in the last block — rocPRIM look-back idiom; NO
// dispatch-order assumption, no spin-wait (cannot hang), graph-capture-safe
// (unlike coop, R4-R6). Staleness audit: each partial cache line has exactly
// one writer (its own chunk block) and its only prior reader is that same
// block, so the fin block's plain loads cannot hit a stale local copy.
__device__ __forceinline__ float interp_wf(const float* wfs, float xn) {
  const float dxg = (float)(2.0 * M_PI / 239.0);
  float t = xn / dxg;
  int f = (int)floorf(t); f = min(max(f, 0), 239);
  int c = (int)ceilf(t);  c = min(max(c, 0), 239);
  float yf = wfs[f], yc = wfs[c];
  if (c == f) return yc;
  float xgf = (float)f * dxg;
  return yf + (yc - yf) * (xn - xgf) / ((float)(c - f) * dxg);
}

__global__ __launch_bounds__(256) void k_colfft_part(
    float2* bufA,   // read 8 rows, then overlay-write partials (no restrict: aliased on purpose)
    const float* __restrict__ delays, const float* __restrict__ wfs_g,
    const float* __restrict__ sos, const float* __restrict__ mask,
    float* __restrict__ acc, unsigned* __restrict__ cnt,
    float2* __restrict__ Xo) {
  __shared__ float2 s[8][512];   // 32768 B EXACTLY — the kernel's only LDS
  int b = blockIdx.x;
  int tid = threadIdx.x;
  float* scratch = (float*)&s[0][0];
  if (b < 1024) {
    // ---------- tvl1 (block-level reduce via s-scratch; 2 atomics/block) ----
    int t = b * 256 + tid;
    float sv = sos[t];
    float m = mask[t];
    int i = t >> 9, j = t & 511;
    float tv = 0.f;
    if (i > 0) tv += fabsf((sv - sos[t - 512]) * m);
    if (j > 0) tv += fabsf((sv - sos[t - 1]) * m);
    float l1 = fabsf(sv - 1550.f) * m;
    float tvb = block_reduce_scratch(tv, scratch);
    float l1b = block_reduce_scratch(l1, scratch + 8);
    if (tid == 0) {
      atomicAdd(&acc[ACC_G(1, b)], tvb);
      atomicAdd(&acc[ACC_G(2, b)], l1b);
    }
    return;
  }
  int job = b - 1024;            // 0..1027
  int v = job >> 2;              // 0..256
  int h = job & 3;               // chunk of 8 channels

  // ---- stage wfs through s, preload delays to registers
  if (tid < NTH) scratch[tid] = wfs_g[tid];
  float dreg[8];
  #pragma unroll
  for (int ch = 0; ch < 8; ++ch) dreg[ch] = delays[h * 8 + ch];
  __syncthreads();

  const float inv_nd = 1.f / 0.02048f;
  const float TWO_PI = 6.28318530717958647692f;
  float fy = (float)(v < 256 ? v : v - 512) * inv_nd;
  float kkA[2];
  float2 zw[2], zwpi[2];   // exp(i kk w), exp(i kk wpi)
  #pragma unroll
  for (int uu = 0; uu < 2; ++uu) {
    int u = tid + 256 * uu;
    float fx = (float)(u < 256 ? u : u - 512) * inv_nd;
    float kk = TWO_PI * sqrtf(fx * fx + fy * fy);
    kkA[uu] = kk;
    float th = atan2f(fy, fx);
    if (th < 0.f) th += TWO_PI;
    float w = interp_wf(scratch, th);
    float thpi = th + PI_F;
    if (thpi >= TWO_PI) thpi -= TWO_PI;
    float wpi = interp_wf(scratch, thpi);
    float snw, csw; __sincosf(kk * w, &snw, &csw);
    zw[uu] = make_float2(csw, snw);
    float snp, csp; __sincosf(kk * wpi, &snp, &csp);
    zwpi[uu] = make_float2(csp, snp);
  }
  __syncthreads();   // all wfs reads done before s is overwritten

  // ---- load this chunk's 8 channels (bit-rev + ifftshifted pad placement)
  for (int e = tid; e < 2048; e += 256) {
    int ch = e >> 8, c = e & 255;
    float2 val = bufA[((size_t)(h * 8 + ch) << 17) + (size_t)v * 256 + c];
    s[ch][SWZ(brev9((c + 384) & 511))] = val;
    s[ch][SWZ(brev9(c + 128))] = make_float2(0.f, 0.f);
  }
  __syncthreads();   // also drains the global loads before overlay-writes later
  fft512_r4_fwd_rows_swz(s, tid);

  // ---- deconv accumulate over this chunk's 8 channels
  float rhsr[2] = {0.f, 0.f}, rhsi[2] = {0.f, 0.f}, lhs[2] = {0.f, 0.f};
  float sY2[2] = {0.f, 0.f}, sYH[2] = {0.f, 0.f};
  #pragma unroll
  for (int uu = 0; uu < 2; ++uu) {
    float kk = kkA[uu];
    float2 w0 = zw[uu], w1 = zwpi[uu];
    int u = SWZ(tid + 256 * uu);
    #pragma unroll
    for (int ch = 0; ch < 8; ++ch) {
      float dl = dreg[ch];
      float sd, cd2;
      __sincosf(kk * dl, &sd, &cd2);
      // H = 0.5*(conj(zd)*zw + zd*conj(zwpi)), zd = exp(i kk d)
      float t0r = cd2 * w0.x + sd * w0.y;
      float t0i = cd2 * w0.y - sd * w0.x;
      float t1r = cd2 * w1.x + sd * w1.y;
      float t1i = sd * w1.x - cd2 * w1.y;
      float Hr = 0.5f * (t0r + t1r);
      float Hi = 0.5f * (t0i + t1i);
      float2 Yv = s[ch][u];
      rhsr[uu] += Yv.x * Hr + Yv.y * Hi;
      rhsi[uu] += Yv.y * Hr - Yv.x * Hi;
      float h2 = Hr * Hr + Hi * Hi;
      float y2 = Yv.x * Yv.x + Yv.y * Yv.y;
      lhs[uu] += h2;
      sY2[uu] += y2;
      sYH[uu] += sqrtf(y2 * h2);
    }
  }

  // ---- X-independent loss term: sum kk^2 * |Y|^2 (Hermitian weight)
  float lw = (v == 0 || v == 256) ? 1.f : 2.f;
  float lsum = (kkA[0] * kkA[0] * sY2[0] + kkA[1] * kkA[1] * sY2[1]) * lw;
  float bs = block_reduce_scratch(lsum, scratch);
  if (tid == 0) atomicAdd(&acc[ACC_G(0, job)], bs);

  // ---- overlay partials into the 4 lowest consumed channel-rows:
  // float index (ch<<18) + (v<<9) + u, ch = h*8+q, q = {rhsr,rhsi,lhs,sYH}
  float* fb = (float*)bufA;
  #pragma unroll
  for (int uu = 0; uu < 2; ++uu) {
    int u = tid + 256 * uu;
    size_t base = ((size_t)v << 9) + u;
    fb[(((size_t)(h * 8 + 0)) << 18) + base] = rhsr[uu];
    fb[(((size_t)(h * 8 + 1)) << 18) + base] = rhsi[uu];
    fb[(((size_t)(h * 8 + 2)) << 18) + base] = lhs[uu];
    fb[(((size_t)(h * 8 + 3)) << 18) + base] = sYH[uu];
  }

  // ---- publish: release fence (every thread), barrier, one atomic
  __threadfence();
  __syncthreads();
  int* flagp = (int*)&s[0][0];
  if (tid == 0) {
    unsigned old = atomicAdd(&cnt[v], 1u);
    flagp[0] = ((old & 3u) == 3u) ? 1 : 0;   // replay-tolerant last-arriver test
  }
  __syncthreads();
  int last = flagp[0];
  __syncthreads();   // everyone read the flag before s is reused
  if (!last) return;

  // ================= fin work for this v (last-arriver block) ==============
  __threadfence();   // acquire side
  float lsum2 = 0.f;
  float2 Xv[2];
  #pragma unroll
  for (int uu = 0; uu < 2; ++uu) {
    int u = tid + 256 * uu;
    float R = 0.f, I = 0.f, L = 0.f, YH = 0.f;
    size_t basei = ((size_t)v << 9) + u;
    #pragma unroll
    for (int h2 = 0; h2 < 4; ++h2) {
      R  += fb[(((size_t)(h2 * 8 + 0)) << 18) + basei];
      I  += fb[(((size_t)(h2 * 8 + 1)) << 18) + basei];
      L  += fb[(((size_t)(h2 * 8 + 2)) << 18) + basei];
      YH += fb[(((size_t)(h2 * 8 + 3)) << 18) + basei];
    }
    float Xr = R / L, Xi = I / L;
    Xv[uu] = make_float2(Xr, Xi);
    float aX = sqrtf(Xr * Xr + Xi * Xi);
    lsum2 += kkA[uu] * kkA[uu] * (aX * aX * L - 2.f * aX * YH);
  }
  float bs2 = block_reduce_scratch(lsum2 * lw, (float*)&s[6][0]);
  if (tid == 0) atomicAdd(&acc[ACC_G(0, v)], bs2);

  // ---- u-axis inverse FFT of this v's X column (padded row in s[0..])
  float2* sr = (float2*)&s[0][0];   // uses 4608 B, disjoint from s[6] scratch
  __syncthreads();                  // reduce done; safe to restage
  sr[PHY(brev9(tid))] = Xv[0];
  sr[PHY(brev9(tid + 256))] = Xv[1];
  __syncthreads();
  fft512_r4_row(sr, tid, +1.f);
  const float sc = 1.f / 512.f;
  float2 o0 = sr[PHY(tid)], o1 = sr[PHY(tid + 256)];
  o0.x *= sc; o0.y *= sc; o1.x *= sc; o1.y *= sc;
  // transposed store: Xo[u][v], Hermitian mirror for v in (0,256)
  Xo[((size_t)tid << 9) + v] = o0;
  Xo[((size_t)(tid + 256) << 9) + v] = o1;
  if (v != 0 && v != 256) {
    int vm = 512 - v;
    Xo[((size_t)tid << 9) + vm] = make_float2(o0.x, -o0.y);
    Xo[((size_t)(tid + 256) << 9) + vm] = make_float2(o1.x, -o1.y);
  }
}

// ---------------- K4: final inverse row FFT (radix-4) + fftshift store -----
// Also finalizes loss (block 0, thread 0): sums the 16 slot-heads per group.
__global__ __launch_bounds__(256) void k_final_rows(const float2* __restrict__ buf,
                                                    float* __restrict__ xrec,
                                                    const float* __restrict__ acc,
                                                    float* __restrict__ lossout) {
  __shared__ float2 s[RSW];
  int arow = blockIdx.x;
  const float2* p = buf + ((size_t)arow << 9);
  int tid = threadIdx.x;
  if (arow == 0 && tid == 0) {
    float a0 = 0.f, a1 = 0.f, a2 = 0.f;
    #pragma unroll
    for (int i = 0; i < 16; ++i) {
      a0 += acc[ACC_G(0, i)];
      a1 += acc[ACC_G(1, i)];
      a2 += acc[ACC_G(2, i)];
    }
    lossout[0] = a0 * (1.f / 8388608.f) + 1e-3f * a1 + 1e-3f * (a2 * (1.f / 262144.f));
  }
  s[PHY(brev9(tid))] = p[tid];
  s[PHY(brev9(tid + 256))] = p[tid + 256];
  __syncthreads();
  fft512_r4_row(s, tid, +1.f);
  int orow = (arow + 256) & 511;
  const float sc = 1.f / 512.f;
  xrec[(orow << 9) + ((tid + 256) & 511)] = s[PHY(tid)].x * sc;
  xrec[(orow << 9) + (tid & 511)] = s[PHY(tid + 256)].x * sc;
}

// ---------------- launch ----------------
extern "C" void kernel_launch(void* const* d_in, const int* in_sizes, int n_in,
                              void* d_out, int out_size, void* d_ws, size_t ws_size,
                              hipStream_t stream) {
  const float* W1 = (const float*)d_in[0];
  const float* b1 = (const float*)d_in[1];
  const float* W2 = (const float*)d_in[2];
  const float* b2 = (const float*)d_in[3];
  const float* W3 = (const float*)d_in[4];
  const float* b3 = (const float*)d_in[5];
  const float* W4 = (const float*)d_in[6];
  const float* b4 = (const float*)d_in[7];
  const float* y_img = (const float*)d_in[8];
  const float* delays = (const float*)d_in[9];
  const float* xq = (const float*)d_in[10];
  const float* yq = (const float*)d_in[11];
  const float* mgrid = (const float*)d_in[12];
  const float* mask = (const float*)d_in[13];
  const int* mask_idx = (const int*)d_in[14];
  const float* x_vec = (const float*)d_in[15];
  const float* y_vec = (const float*)d_in[16];
  const int M = in_sizes[14];
  const int nMlpB = (M + 2 * MLP_P - 1) / (2 * MLP_P);

  float* out = (float*)d_out;
  float* xrec = out;                    // 262144
  float* sos = out + SOS_ELEMS;         // 262144
  float* loss = out + 2 * SOS_ELEMS;    // 1

  char* wsb = (char*)d_ws;
  float* acc = (float*)wsb;                                     // 768 floats (3 groups x 16 lines)
  unsigned* cnt = (unsigned*)(wsb + 3072);                      // 257 counters (zeroed by k_front)
  float* wfs = (float*)(wsb + 4608);                            // 240 floats
  float2* bufA = (float2*)(wsb + 8192);                         // 32ch x 131072 c64
  float2* bufX = (float2*)(wsb + 8192 + (size_t)NDEL * 512 * 256 * sizeof(float2)); // 2 MB

  k_front<<<nMlpB + 1024, 256, 0, stream>>>(W1, b1, W2, b2, W3, b3, W4, b4,
                                            mgrid, mask_idx, mask, M, nMlpB,
                                            sos, acc, y_img, bufA);
  k_side<<<NTH, 256, 0, stream>>>(sos, xq, yq, x_vec, y_vec, wfs);
  k_colfft_part<<<1024 + 1028, 256, 0, stream>>>(bufA, delays, wfs, sos, mask,
                                                 acc, cnt, bufX);
  k_final_rows<<<512, 256, 0, stream>>>(bufX, xrec, acc, loss);
}

// Round 13
// 178.828 us; speedup vs baseline: 1.9784x; 1.9784x over previous
//
#include <hip/hip_runtime.h>
#include <hip/hip_bf16.h>
#include <math.h>

// ---------------- constants ----------------
#define NP 512
#define NIMG 256
#define NDEL 32
#define NTH 240
#define NINT 250
#define SOS_ELEMS (512*512)
#define MLP_P 32
// swizzled physical index for FFT LDS rows (padded variant, 576/row)
#define PHY(i) ((i) + ((i) >> 3))
#define RSW 576   // PHY(511)=574 -> row array size
// XOR-swizzle for the UNPADDED 512/row variant (k_colfft_part 32KB diet):
// bijective on [0,512): bits 3..8 preserved, bits 0..2 ^= bits 6..8.
// Breaks the "addresses equal mod 64" bank catastrophe of bit-rev scatter.
#define SWZ(i) ((i) ^ (((i) >> 6) & 7))
#define PI_F 3.14159265358979323846f

// ===================== session ledger (do not re-try) =======================
// R4-R6: cooperative launch -> 3 bit-identical loss failures. NEVER.
// R7: 4-row part chunks + spread sos fill -> +13us (preamble doubling).
// R9: wave-level same-line atomics -> +116us (coherent-point serialization).
// R11/R12: fused fin via per-block __threadfence (device scope) -> +172us:
//   each fence forces an L2 writeback on this 8-XCD chip (WRITE_SIZE 2x).
//   Cross-block dataflow goes through KERNEL BOUNDARIES ONLY.
// R10 = verified optimum (181.1us): this file.
// ===========================================================================

__device__ __forceinline__ int brev9(int i) { return (int)(__brev((unsigned)i) >> 23); }

__device__ __forceinline__ float block_reduce_any(float v) {
  #pragma unroll
  for (int o = 32; o > 0; o >>= 1) v += __shfl_down(v, o, 64);
  __shared__ float red[16];
  int lane = threadIdx.x & 63, wid = threadIdx.x >> 6;
  __syncthreads();
  if (lane == 0) red[wid] = v;
  __syncthreads();
  float r = 0.f;
  if (threadIdx.x == 0) {
    int nw = blockDim.x >> 6;
    for (int i = 0; i < nw; ++i) r += red[i];
  }
  return r;
}

// block reduce using caller-provided LDS scratch (>=4 floats) — for kernels
// whose LDS budget is exact (no room for a static red[]). 256-thread blocks.
__device__ __forceinline__ float block_reduce_scratch(float v, float* scratch) {
  #pragma unroll
  for (int o = 32; o > 0; o >>= 1) v += __shfl_down(v, o, 64);
  int lane = threadIdx.x & 63, wid = threadIdx.x >> 6;
  __syncthreads();
  if (lane == 0) scratch[wid] = v;
  __syncthreads();
  float r = 0.f;
  if (threadIdx.x == 0) {
    #pragma unroll
    for (int i = 0; i < 4; ++i) r += scratch[i];
  }
  return r;
}

// ---- radix-4 FFT core butterfly (sign = -1 fwd, +1 inv) ----
__device__ __forceinline__ void r4_bfly(float2& x0, float2& x1, float2& x2, float2& x3,
                                        float c1, float s1n, float c2, float s2n, float sign) {
  float t1x = x1.x * c1 - x1.y * s1n, t1y = x1.x * s1n + x1.y * c1;
  float y0x = x0.x + t1x, y0y = x0.y + t1y;
  float y1x = x0.x - t1x, y1y = x0.y - t1y;
  float t3x = x3.x * c1 - x3.y * s1n, t3y = x3.x * s1n + x3.y * c1;
  float y2x = x2.x + t3x, y2y = x2.y + t3y;
  float y3x = x2.x - t3x, y3y = x2.y - t3y;
  float t2x = y2x * c2 - y2y * s2n, t2y = y2x * s2n + y2y * c2;
  float ux = y3x * c2 - y3y * s2n, uy = y3x * s2n + y3y * c2;
  float t4x = -sign * uy, t4y = sign * ux;   // rotate by sign*i (fwd: -i)
  x0 = make_float2(y0x + t2x, y0y + t2y);
  x2 = make_float2(y0x - t2x, y0y - t2y);
  x1 = make_float2(y1x + t4x, y1y + t4y);
  x3 = make_float2(y1x - t4x, y1y - t4y);
}

// radix-4 FFT, 512 pts x 8 rows, 256 threads, XOR-swizzled UNPADDED rows.
__device__ __forceinline__ void fft512_r4_fwd_rows_swz(float2 (*s)[512], int lt) {
  #pragma unroll
  for (int pass = 0; pass < 4; ++pass) {
    const int sh = 2 * pass;
    const int h = 1 << sh;
    int p = lt & 127;
    int rbase = (lt >> 7) << 2;
    int j = p & (h - 1);
    int g = p >> sh;
    int base = (g << (sh + 2)) + j;
    int i0 = SWZ(base), i1 = SWZ(base + h), i2 = SWZ(base + 2 * h), i3 = SWZ(base + 3 * h);
    float ang1 = -PI_F * (float)j / (float)h;
    float s1n, c1; __sincosf(ang1, &s1n, &c1);
    float s2n, c2; __sincosf(0.5f * ang1, &s2n, &c2);
    #pragma unroll
    for (int rr = 0; rr < 4; ++rr) {
      int r = rbase + rr;
      float2 x0 = s[r][i0], x1 = s[r][i1], x2 = s[r][i2], x3 = s[r][i3];
      r4_bfly(x0, x1, x2, x3, c1, s1n, c2, s2n, -1.f);
      s[r][i0] = x0; s[r][i1] = x1; s[r][i2] = x2; s[r][i3] = x3;
    }
    __syncthreads();
  }
  {
    int p = lt;
    int i1 = SWZ(p), i2 = SWZ(p + 256);
    float ang = -PI_F * (float)p * (1.f / 256.f);
    float sn, cs; __sincosf(ang, &sn, &cs);
    #pragma unroll
    for (int r = 0; r < 8; ++r) {
      float2 a = s[r][i1], b = s[r][i2];
      float tr = b.x * cs - b.y * sn;
      float ti = b.x * sn + b.y * cs;
      s[r][i1] = make_float2(a.x + tr, a.y + ti);
      s[r][i2] = make_float2(a.x - tr, a.y - ti);
    }
    __syncthreads();
  }
}

// radix-4 FFT, 512 pts x 4 rows (packed real pairs), 256 threads, padded.
__device__ __forceinline__ void fft512_r4_fwd_rows4(float2 (*s)[RSW], int tid) {
  #pragma unroll
  for (int pass = 0; pass < 4; ++pass) {
    const int sh = 2 * pass;
    const int h = 1 << sh;
    int p = tid & 127;
    int rbase = (tid >> 7) << 1;
    int j = p & (h - 1);
    int g = p >> sh;
    int base = (g << (sh + 2)) + j;
    int i0 = PHY(base), i1 = PHY(base + h), i2 = PHY(base + 2 * h), i3 = PHY(base + 3 * h);
    float ang1 = -PI_F * (float)j / (float)h;
    float s1n, c1; __sincosf(ang1, &s1n, &c1);
    float s2n, c2; __sincosf(0.5f * ang1, &s2n, &c2);
    #pragma unroll
    for (int rr = 0; rr < 2; ++rr) {
      int r = rbase + rr;
      float2 x0 = s[r][i0], x1 = s[r][i1], x2 = s[r][i2], x3 = s[r][i3];
      r4_bfly(x0, x1, x2, x3, c1, s1n, c2, s2n, -1.f);
      s[r][i0] = x0; s[r][i1] = x1; s[r][i2] = x2; s[r][i3] = x3;
    }
    __syncthreads();
  }
  {
    int p = tid;
    int i1 = PHY(p), i2 = PHY(p + 256);
    float ang = -PI_F * (float)p * (1.f / 256.f);
    float sn, cs; __sincosf(ang, &sn, &cs);
    #pragma unroll
    for (int r = 0; r < 4; ++r) {
      float2 a = s[r][i1], b = s[r][i2];
      float tr = b.x * cs - b.y * sn;
      float ti = b.x * sn + b.y * cs;
      s[r][i1] = make_float2(a.x + tr, a.y + ti);
      s[r][i2] = make_float2(a.x - tr, a.y - ti);
    }
    __syncthreads();
  }
}

// radix-4 FFT, single 512-pt row, 256 threads, padded, sign-param.
__device__ __forceinline__ void fft512_r4_row(float2* s, int tid, float sign) {
  #pragma unroll
  for (int pass = 0; pass < 4; ++pass) {
    const int sh = 2 * pass;
    const int h = 1 << sh;
    if (tid < 128) {
      int j = tid & (h - 1);
      int g = tid >> sh;
      int base = (g << (sh + 2)) + j;
      int i0 = PHY(base), i1 = PHY(base + h), i2 = PHY(base + 2 * h), i3 = PHY(base + 3 * h);
      float ang1 = sign * PI_F * (float)j / (float)h;
      float s1n, c1; __sincosf(ang1, &s1n, &c1);
      float s2n, c2; __sincosf(0.5f * ang1, &s2n, &c2);
      float2 x0 = s[i0], x1 = s[i1], x2 = s[i2], x3 = s[i3];
      r4_bfly(x0, x1, x2, x3, c1, s1n, c2, s2n, sign);
      s[i0] = x0; s[i1] = x1; s[i2] = x2; s[i3] = x3;
    }
    __syncthreads();
  }
  {
    int i1 = PHY(tid), i2 = PHY(tid + 256);
    float ang = sign * PI_F * (float)tid * (1.f / 256.f);
    float sn, cs; __sincosf(ang, &sn, &cs);
    float2 a = s[i1], b = s[i2];
    float tr = b.x * cs - b.y * sn;
    float ti = b.x * sn + b.y * cs;
    s[i1] = make_float2(a.x + tr, a.y + ti);
    s[i2] = make_float2(a.x - tr, a.y - ti);
    __syncthreads();
  }
}

// acc layout in workspace (floats): 3 quantity groups x 16 slots x 16-float
// (64B) stride — atomics spread over 16 cache lines per group (R9 lesson:
// same-line atomics serialize ~10ns each at the coherent point).
#define ACC_G(g, slot) ((g) * 256 + ((slot) & 15) * 16)

// ---------------- K_front: FUSED {2x MLP tile | fwdT} -----------------------
// R3-verified. DO NOT retile the 128-thread MLP schedule (prior session
// R10/R11/R15 regressed — incl. 16-row wbuf); DO NOT spread the sos fill
// into fwdT blocks (R7 regressed); NO cooperative launch (R4-R6).
__global__ __launch_bounds__(256) void k_front(
    const float* __restrict__ W1, const float* __restrict__ b1,
    const float* __restrict__ W2, const float* __restrict__ b2,
    const float* __restrict__ W3, const float* __restrict__ b3,
    const float* __restrict__ W4v, const float* __restrict__ b4,
    const float* __restrict__ mgrid, const int* __restrict__ mask_idx,
    const float* __restrict__ mask, int M, int nMlpB,
    float* __restrict__ sos, float* __restrict__ acc,
    const float* __restrict__ y_img, float2* __restrict__ bufA) {
  __shared__ char raw[43008];   // MLP: 33792 hbuf + 8448 wbuf + 512 xy = 42752; fwdT: 18432
  int bid = blockIdx.x;
  int tid = threadIdx.x;
  if (bid < nMlpB) {
    // ================= two MLP tiles (64 points) =================
    float (*hbuf)[MLP_P][132] = (float (*)[MLP_P][132])raw;          // [2][32][132]
    float (*wbuf)[8][132]     = (float (*)[8][132])(raw + 33792);    // [2][8][132]
    float (*xy2)[2]           = (float (*)[2])(raw + 33792 + 8448);  // [64][2]
    int half = tid >> 7, lt = tid & 127;
    int base = bid * (2 * MLP_P) + half * MLP_P;
    if (lt < MLP_P * 2) {
      int p = lt >> 1, c = lt & 1;
      float v = 0.f;
      if (base + p < M) v = mgrid[(base + p) * 2 + c];
      xy2[half * MLP_P + p][c] = v;
    }
    if (bid == 0) {
      for (int e = tid; e < 768; e += 256) acc[e] = 0.f;
    }
    for (int slab = bid; slab < 1024; slab += nMlpB) {
      int t = slab * 256 + tid;
      if (mask[t] == 0.f) sos[t] = 1499.363f;
    }
    __syncthreads();
    for (int e = lt; e < MLP_P * 128; e += 128) {
      int p = e >> 7, j = e & 127;
      hbuf[half][p][j] = __sinf(30.f * (xy2[half * MLP_P + p][0] * W1[j] +
                                        xy2[half * MLP_P + p][1] * W1[128 + j] + b1[j]));
    }
    __syncthreads();

    int jg = lt & 15, pg = lt >> 4;
    int jA = jg * 4, jB = 64 + jg * 4;
    int p0 = pg * 4;
    int wr = tid >> 4, wc = (tid & 15) << 3;   // wbuf writer coords, valid for tid<128
    #pragma unroll
    for (int layer = 0; layer < 2; ++layer) {
      const float* Wg = layer ? W3 : W2;
      const float* bb = layer ? b3 : b2;
      float acr[4][8];
      #pragma unroll
      for (int i = 0; i < 4; ++i)
        #pragma unroll
        for (int j = 0; j < 8; ++j) acr[i][j] = 0.f;

      float4 pre1, pre2;
      if (tid < 128) {
        pre1 = *(const float4*)&Wg[wr * 128 + wc];
        pre2 = *(const float4*)&Wg[wr * 128 + wc + 4];
      }
      for (int c = 0; c < 16; ++c) {
        if (tid < 128) {
          *(float4*)&wbuf[c & 1][wr][wc] = pre1;
          *(float4*)&wbuf[c & 1][wr][wc + 4] = pre2;
        }
        __syncthreads();
        if (tid < 128 && c < 15) {
          pre1 = *(const float4*)&Wg[((c + 1) * 8 + wr) * 128 + wc];
          pre2 = *(const float4*)&Wg[((c + 1) * 8 + wr) * 128 + wc + 4];
        }
        int k0 = c * 8;
        float hreg[4][8];
        #pragma unroll
        for (int i = 0; i < 4; ++i) {
          float4 ha = *(const float4*)&hbuf[half][p0 + i][k0];
          float4 hb = *(const float4*)&hbuf[half][p0 + i][k0 + 4];
          hreg[i][0] = ha.x; hreg[i][1] = ha.y; hreg[i][2] = ha.z; hreg[i][3] = ha.w;
          hreg[i][4] = hb.x; hreg[i][5] = hb.y; hreg[i][6] = hb.z; hreg[i][7] = hb.w;
        }
        #pragma unroll
        for (int kk = 0; kk < 8; ++kk) {
          float4 wa = *(const float4*)&wbuf[c & 1][kk][jA];
          float4 wb = *(const float4*)&wbuf[c & 1][kk][jB];
          float w8[8] = {wa.x, wa.y, wa.z, wa.w, wb.x, wb.y, wb.z, wb.w};
          #pragma unroll
          for (int i = 0; i < 4; ++i) {
            float hv = hreg[i][kk];
            #pragma unroll
            for (int j = 0; j < 8; ++j) acr[i][j] += hv * w8[j];
          }
        }
      }
      float breg[8];
      #pragma unroll
      for (int j = 0; j < 4; ++j) { breg[j] = bb[jA + j]; breg[4 + j] = bb[jB + j]; }
      __syncthreads();
      #pragma unroll
      for (int i = 0; i < 4; ++i) {
        float o[8];
        #pragma unroll
        for (int j = 0; j < 8; ++j) o[j] = __sinf(30.f * (acr[i][j] + breg[j]));
        *(float4*)&hbuf[half][p0 + i][jA] = make_float4(o[0], o[1], o[2], o[3]);
        *(float4*)&hbuf[half][p0 + i][jB] = make_float4(o[4], o[5], o[6], o[7]);
      }
      __syncthreads();
    }
    {
      int p = lt >> 2, q = lt & 3;
      float s = 0.f;
      #pragma unroll
      for (int k = 0; k < 32; k += 4) {
        float4 h4 = *(const float4*)&hbuf[half][p][q * 32 + k];
        float4 w4 = *(const float4*)&W4v[q * 32 + k];
        s += h4.x * w4.x + h4.y * w4.y + h4.z * w4.z + h4.w * w4.w;
      }
      s += __shfl_down(s, 1, 64);
      s += __shfl_down(s, 2, 64);
      if (q == 0 && base + p < M)
        sos[mask_idx[base + p]] = (s + b4[0]) * 170.f + 1550.f;
    }
  } else {
    // ================= fwdT: real-pair packed v-axis FFT, Hermitian store ====
    float2 (*s)[RSW] = (float2 (*)[RSW])raw;   // [4][RSW]
    int fb = bid - nMlpB;
    int rt = fb & 31;
    int d = fb >> 5;
    const float INV2S2 = (float)(0.6931471805599453 / 1406.25);
    for (int e = tid; e < 2048; e += 256) {
      int i = e >> 8, c = e & 255;
      int r = rt * 8 + i;
      float axr = (float)r - 127.5f;
      float axc = (float)c - 127.5f;
      float g = __expf(-(axr * axr + axc * axc) * INV2S2);
      float val = y_img[((size_t)d << 16) + (r << 8) + c] * g;
      int p = i >> 1, comp = i & 1;
      ((float*)&s[p][PHY(brev9((c + 384) & 511))])[comp] = val;
      ((float*)&s[p][PHY(brev9(c + 128))])[comp] = 0.f;
    }
    __syncthreads();
    fft512_r4_fwd_rows4(s, tid);
    float2* outp = bufA + ((size_t)d << 17) + rt * 8;
    for (int e = tid; e < 2056; e += 256) {
      int i = e & 7, v = e >> 3;
      int p = i >> 1, comp = i & 1;
      float2 Zv = s[p][PHY(v)];
      float2 Zm = s[p][PHY((512 - v) & 511)];
      float2 Yv;
      if (comp == 0) Yv = make_float2(0.5f * (Zv.x + Zm.x), 0.5f * (Zv.y - Zm.y));
      else           Yv = make_float2(0.5f * (Zv.y + Zm.y), 0.5f * (Zm.x - Zv.x));
      outp[(size_t)v * 256 + i] = Yv;
    }
  }
}

// ---------------- K_side: wavefront only ----------------
__global__ __launch_bounds__(256) void k_side(
    const float* __restrict__ sos, const float* __restrict__ xq_p,
    const float* __restrict__ yq_p, const float* __restrict__ x_vec,
    const float* __restrict__ y_vec, float* __restrict__ wfs) {
  int i = blockIdx.x;
  int j = threadIdx.x;
  float xq = xq_p[0], yq = yq_p[0];
  float r = sqrtf(xq * xq + yq * yq);
  float phi = atan2f(xq, yq);
  float th = (float)((double)i * (2.0 * M_PI / 239.0));
  float sn = sinf(th - phi), cd = cosf(th - phi);
  const float R2 = 0.008f * 0.008f;
  float disc = fmaxf(R2 - (r * sn) * (r * sn), 0.f);
  float sq = sqrtf(disc);
  float l_in = sq + r * cd;
  float l_out = 2.f * sq * (cd >= 0.f ? 1.f : 0.f);
  float l = (r < 0.008f) ? l_in : l_out;
  float x0 = x_vec[0], dx = x_vec[1] - x_vec[0];
  float y0 = y_vec[0], dy = y_vec[1] - y_vec[0];
  float sinth = sinf(th), costh = cosf(th);
  float contrib = 0.f;
  if (j < NINT) {
    float sj = (float)j * (1.f / 249.f);
    int xi = (int)rintf((xq - l * sj * sinth - x0) / dx);
    int yi = (int)rintf((yq - l * sj * costh - y0) / dy);
    float sv = sos[(((-yi) & 511) << 9) + (xi & 511)];
    float f = 1.f - 1500.f / sv;
    float wgt = (j == 0 || j == NINT - 1) ? 0.5f : 1.f;
    contrib = wgt * f;
  }
  float tot = block_reduce_any(contrib);
  if (threadIdx.x == 0) wfs[i] = tot * l * (1.f / 249.f);
}

// ---------------- K3a: per-(v, 8ch-chunk) u-axis FFT + deconv partials -----
// R10 geometry (verified 181.1us): 32KB LDS EXACTLY -> 5 blocks/CU = 1280
// slots >= 1028 heavy jobs -> single round (257 prime: slots must exceed
// 257k). Bank safety via SWZ. Block-level loss reduce, ONE atomic per block,
// spread over 16 lines. Blocks [0,1024)=tvl1 light first; [1024,2052)=heavy.
__device__ __forceinline__ float interp_wf(const float* wfs, float xn) {
  const float dxg = (float)(2.0 * M_PI / 239.0);
  float t = xn / dxg;
  int f = (int)floorf(t); f = min(max(f, 0), 239);
  int c = (int)ceilf(t);  c = min(max(c, 0), 239);
  float yf = wfs[f], yc = wfs[c];
  if (c == f) return yc;
  float xgf = (float)f * dxg;
  return yf + (yc - yf) * (xn - xgf) / ((float)(c - f) * dxg);
}

__global__ __launch_bounds__(256) void k_colfft_part(
    float2* bufA,   // read 8 rows, then overlay-write partials (no restrict: aliased on purpose)
    const float* __restrict__ delays, const float* __restrict__ wfs_g,
    const float* __restrict__ sos, const float* __restrict__ mask,
    float* __restrict__ acc) {
  __shared__ float2 s[8][512];   // 32768 B EXACTLY — the kernel's only LDS
  int b = blockIdx.x;
  int tid = threadIdx.x;
  float* scratch = (float*)&s[0][0];
  if (b < 1024) {
    // ---------- tvl1 (block-level reduce via s-scratch; 2 atomics/block) ----
    int t = b * 256 + tid;
    float sv = sos[t];
    float m = mask[t];
    int i = t >> 9, j = t & 511;
    float tv = 0.f;
    if (i > 0) tv += fabsf((sv - sos[t - 512]) * m);
    if (j > 0) tv += fabsf((sv - sos[t - 1]) * m);
    float l1 = fabsf(sv - 1550.f) * m;
    float tvb = block_reduce_scratch(tv, scratch);
    float l1b = block_reduce_scratch(l1, scratch + 8);
    if (tid == 0) {
      atomicAdd(&acc[ACC_G(1, b)], tvb);
      atomicAdd(&acc[ACC_G(2, b)], l1b);
    }
    return;
  }
  int job = b - 1024;            // 0..1027
  int v = job >> 2;              // 0..256
  int h = job & 3;               // chunk of 8 channels

  // ---- stage wfs through s, preload delays to registers
  if (tid < NTH) scratch[tid] = wfs_g[tid];
  float dreg[8];
  #pragma unroll
  for (int ch = 0; ch < 8; ++ch) dreg[ch] = delays[h * 8 + ch];
  __syncthreads();

  const float inv_nd = 1.f / 0.02048f;
  const float TWO_PI = 6.28318530717958647692f;
  float fy = (float)(v < 256 ? v : v - 512) * inv_nd;
  float kkA[2];
  float2 zw[2], zwpi[2];   // exp(i kk w), exp(i kk wpi)
  #pragma unroll
  for (int uu = 0; uu < 2; ++uu) {
    int u = tid + 256 * uu;
    float fx = (float)(u < 256 ? u : u - 512) * inv_nd;
    float kk = TWO_PI * sqrtf(fx * fx + fy * fy);
    kkA[uu] = kk;
    float th = atan2f(fy, fx);
    if (th < 0.f) th += TWO_PI;
    float w = interp_wf(scratch, th);
    float thpi = th + PI_F;
    if (thpi >= TWO_PI) thpi -= TWO_PI;
    float wpi = interp_wf(scratch, thpi);
    float snw, csw; __sincosf(kk * w, &snw, &csw);
    zw[uu] = make_float2(csw, snw);
    float snp, csp; __sincosf(kk * wpi, &snp, &csp);
    zwpi[uu] = make_float2(csp, snp);
  }
  __syncthreads();   // all wfs reads done before s is overwritten

  // ---- load this chunk's 8 channels (bit-rev + ifftshifted pad placement)
  for (int e = tid; e < 2048; e += 256) {
    int ch = e >> 8, c = e & 255;
    float2 val = bufA[((size_t)(h * 8 + ch) << 17) + (size_t)v * 256 + c];
    s[ch][SWZ(brev9((c + 384) & 511))] = val;
    s[ch][SWZ(brev9(c + 128))] = make_float2(0.f, 0.f);
  }
  __syncthreads();   // also drains the global loads before overlay-writes later
  fft512_r4_fwd_rows_swz(s, tid);

  // ---- deconv accumulate over this chunk's 8 channels
  float rhsr[2] = {0.f, 0.f}, rhsi[2] = {0.f, 0.f}, lhs[2] = {0.f, 0.f};
  float sY2[2] = {0.f, 0.f}, sYH[2] = {0.f, 0.f};
  #pragma unroll
  for (int uu = 0; uu < 2; ++uu) {
    float kk = kkA[uu];
    float2 w0 = zw[uu], w1 = zwpi[uu];
    int u = SWZ(tid + 256 * uu);
    #pragma unroll
    for (int ch = 0; ch < 8; ++ch) {
      float dl = dreg[ch];
      float sd, cd2;
      __sincosf(kk * dl, &sd, &cd2);
      // H = 0.5*(conj(zd)*zw + zd*conj(zwpi)), zd = exp(i kk d)
      float t0r = cd2 * w0.x + sd * w0.y;
      float t0i = cd2 * w0.y - sd * w0.x;
      float t1r = cd2 * w1.x + sd * w1.y;
      float t1i = sd * w1.x - cd2 * w1.y;
      float Hr = 0.5f * (t0r + t1r);
      float Hi = 0.5f * (t0i + t1i);
      float2 Yv = s[ch][u];
      rhsr[uu] += Yv.x * Hr + Yv.y * Hi;
      rhsi[uu] += Yv.y * Hr - Yv.x * Hi;
      float h2 = Hr * Hr + Hi * Hi;
      float y2 = Yv.x * Yv.x + Yv.y * Yv.y;
      lhs[uu] += h2;
      sY2[uu] += y2;
      sYH[uu] += sqrtf(y2 * h2);
    }
  }

  // ---- X-independent loss term: sum kk^2 * |Y|^2 (Hermitian weight)
  float lw = (v == 0 || v == 256) ? 1.f : 2.f;
  float lsum = (kkA[0] * kkA[0] * sY2[0] + kkA[1] * kkA[1] * sY2[1]) * lw;
  float bs = block_reduce_scratch(lsum, scratch);
  if (tid == 0) atomicAdd(&acc[ACC_G(0, job)], bs);

  // ---- overlay partials into the 4 lowest consumed channel-rows:
  // float index (ch<<18) + (v<<9) + u, ch = h*8+q, q = {rhsr,rhsi,lhs,sYH}
  float* fb = (float*)bufA;
  #pragma unroll
  for (int uu = 0; uu < 2; ++uu) {
    int u = tid + 256 * uu;
    size_t base = ((size_t)v << 9) + u;
    fb[(((size_t)(h * 8 + 0)) << 18) + base] = rhsr[uu];
    fb[(((size_t)(h * 8 + 1)) << 18) + base] = rhsi[uu];
    fb[(((size_t)(h * 8 + 2)) << 18) + base] = lhs[uu];
    fb[(((size_t)(h * 8 + 3)) << 18) + base] = sYH[uu];
  }
}

// ---------------- K3b: combine partials + X + loss + u-ifft + store --------
__global__ __launch_bounds__(256) void k_colfft_fin(
    const float* __restrict__ bufP, float2* __restrict__ Xo,
    float* __restrict__ acc) {
  __shared__ float2 s[RSW];
  int v = blockIdx.x;            // 0..256
  int tid = threadIdx.x;
  const float inv_nd = 1.f / 0.02048f;
  const float TWO_PI = 6.28318530717958647692f;
  float fy = (float)(v < 256 ? v : v - 512) * inv_nd;
  float lw = (v == 0 || v == 256) ? 1.f : 2.f;
  float lsum = 0.f;
  float2 Xv[2];
  #pragma unroll
  for (int uu = 0; uu < 2; ++uu) {
    int u = tid + 256 * uu;
    float fx = (float)(u < 256 ? u : u - 512) * inv_nd;
    float kk2 = TWO_PI * TWO_PI * (fx * fx + fy * fy);
    float R = 0.f, I = 0.f, L = 0.f, YH = 0.f;
    size_t base = ((size_t)v << 9) + u;
    #pragma unroll
    for (int h = 0; h < 4; ++h) {
      R  += bufP[(((size_t)(h * 8 + 0)) << 18) + base];
      I  += bufP[(((size_t)(h * 8 + 1)) << 18) + base];
      L  += bufP[(((size_t)(h * 8 + 2)) << 18) + base];
      YH += bufP[(((size_t)(h * 8 + 3)) << 18) + base];
    }
    float Xr = R / L, Xi = I / L;
    Xv[uu] = make_float2(Xr, Xi);
    float aX = sqrtf(Xr * Xr + Xi * Xi);
    lsum += kk2 * (aX * aX * L - 2.f * aX * YH);   // |Y|^2 term added in K3a
  }
  float bs = block_reduce_any(lsum * lw);
  if (tid == 0) atomicAdd(&acc[ACC_G(0, v)], bs);

  // ---- u-axis inverse FFT of this v's X column
  s[PHY(brev9(tid))] = Xv[0];
  s[PHY(brev9(tid + 256))] = Xv[1];
  __syncthreads();
  fft512_r4_row(s, tid, +1.f);
  const float sc = 1.f / 512.f;
  float2 o0 = s[PHY(tid)], o1 = s[PHY(tid + 256)];
  o0.x *= sc; o0.y *= sc; o1.x *= sc; o1.y *= sc;
  // transposed store: Xo[u][v], Hermitian mirror for v in (0,256)
  Xo[((size_t)tid << 9) + v] = o0;
  Xo[((size_t)(tid + 256) << 9) + v] = o1;
  if (v != 0 && v != 256) {
    int vm = 512 - v;
    Xo[((size_t)tid << 9) + vm] = make_float2(o0.x, -o0.y);
    Xo[((size_t)(tid + 256) << 9) + vm] = make_float2(o1.x, -o1.y);
  }
}

// ---------------- K4: final inverse row FFT (radix-4) + fftshift store -----
// Also finalizes loss (block 0, thread 0): sums the 16 slot-heads per group.
__global__ __launch_bounds__(256) void k_final_rows(const float2* __restrict__ buf,
                                                    float* __restrict__ xrec,
                                                    const float* __restrict__ acc,
                                                    float* __restrict__ lossout) {
  __shared__ float2 s[RSW];
  int arow = blockIdx.x;
  const float2* p = buf + ((size_t)arow << 9);
  int tid = threadIdx.x;
  if (arow == 0 && tid == 0) {
    float a0 = 0.f, a1 = 0.f, a2 = 0.f;
    #pragma unroll
    for (int i = 0; i < 16; ++i) {
      a0 += acc[ACC_G(0, i)];
      a1 += acc[ACC_G(1, i)];
      a2 += acc[ACC_G(2, i)];
    }
    lossout[0] = a0 * (1.f / 8388608.f) + 1e-3f * a1 + 1e-3f * (a2 * (1.f / 262144.f));
  }
  s[PHY(brev9(tid))] = p[tid];
  s[PHY(brev9(tid + 256))] = p[tid + 256];
  __syncthreads();
  fft512_r4_row(s, tid, +1.f);
  int orow = (arow + 256) & 511;
  const float sc = 1.f / 512.f;
  xrec[(orow << 9) + ((tid + 256) & 511)] = s[PHY(tid)].x * sc;
  xrec[(orow << 9) + (tid & 511)] = s[PHY(tid + 256)].x * sc;
}

// ---------------- launch ----------------
extern "C" void kernel_launch(void* const* d_in, const int* in_sizes, int n_in,
                              void* d_out, int out_size, void* d_ws, size_t ws_size,
                              hipStream_t stream) {
  const float* W1 = (const float*)d_in[0];
  const float* b1 = (const float*)d_in[1];
  const float* W2 = (const float*)d_in[2];
  const float* b2 = (const float*)d_in[3];
  const float* W3 = (const float*)d_in[4];
  const float* b3 = (const float*)d_in[5];
  const float* W4 = (const float*)d_in[6];
  const float* b4 = (const float*)d_in[7];
  const float* y_img = (const float*)d_in[8];
  const float* delays = (const float*)d_in[9];
  const float* xq = (const float*)d_in[10];
  const float* yq = (const float*)d_in[11];
  const float* mgrid = (const float*)d_in[12];
  const float* mask = (const float*)d_in[13];
  const int* mask_idx = (const int*)d_in[14];
  const float* x_vec = (const float*)d_in[15];
  const float* y_vec = (const float*)d_in[16];
  const int M = in_sizes[14];
  const int nMlpB = (M + 2 * MLP_P - 1) / (2 * MLP_P);

  float* out = (float*)d_out;
  float* xrec = out;                    // 262144
  float* sos = out + SOS_ELEMS;         // 262144
  float* loss = out + 2 * SOS_ELEMS;    // 1

  char* wsb = (char*)d_ws;
  float* acc = (float*)wsb;                                     // 768 floats (3 groups x 16 lines)
  float* wfs = (float*)(wsb + 3072);                            // 240 floats
  float2* bufA = (float2*)(wsb + 4096);                         // 32ch x 131072 c64
  float2* bufX = (float2*)(wsb + 4096 + (size_t)NDEL * 512 * 256 * sizeof(float2)); // 2 MB

  k_front<<<nMlpB + 1024, 256, 0, stream>>>(W1, b1, W2, b2, W3, b3, W4, b4,
                                            mgrid, mask_idx, mask, M, nMlpB,
                                            sos, acc, y_img, bufA);
  k_side<<<NTH, 256, 0, stream>>>(sos, xq, yq, x_vec, y_vec, wfs);
  k_colfft_part<<<1024 + 1028, 256, 0, stream>>>(bufA, delays, wfs, sos, mask, acc);
  k_colfft_fin<<<257, 256, 0, stream>>>((const float*)bufA, bufX, acc);
  k_final_rows<<<512, 256, 0, stream>>>(bufX, xrec, acc, loss);
}

// Round 14
// 178.429 us; speedup vs baseline: 1.9828x; 1.0022x over previous
//
#include <hip/hip_runtime.h>
#include <hip/hip_bf16.h>
#include <math.h>

// ---------------- constants ----------------
#define NP 512
#define NIMG 256
#define NDEL 32
#define NTH 240
#define NINT 250
#define SOS_ELEMS (512*512)
#define MLP_P 32
// swizzled physical index for FFT LDS rows (padded variant, 576/row)
#define PHY(i) ((i) + ((i) >> 3))
#define RSW 576   // PHY(511)=574 -> row array size
// XOR-swizzle for the UNPADDED 512/row variant (k_colfft_part 32KB diet):
// bijective on [0,512): bits 3..8 preserved, bits 0..2 ^= bits 6..8.
// Breaks the "addresses equal mod 64" bank catastrophe of bit-rev scatter.
#define SWZ(i) ((i) ^ (((i) >> 6) & 7))
#define PI_F 3.14159265358979323846f

// ===================== session ledger (do not re-try) =======================
// R4-R6: cooperative launch -> 3 bit-identical loss failures. NEVER.
// R7: 4-row part chunks + spread sos fill -> +13us (preamble doubling).
// R9: wave-level same-line atomics -> +116us (coherent-point serialization).
// R11/R12: fused fin via per-block __threadfence (device scope) -> +172us:
//   each fence forces an L2 writeback on this 8-XCD chip (WRITE_SIZE 2x).
//   Cross-block dataflow goes through KERNEL BOUNDARIES ONLY.
// R13 = verified optimum (178.8us). R14 = + paired final rows (Z rows are
//   conjugate-symmetric in v BY CONSTRUCTION of fin's mirror store, so two
//   real-output IFFTs pack into one complex IFFT).
// ===========================================================================

__device__ __forceinline__ int brev9(int i) { return (int)(__brev((unsigned)i) >> 23); }

__device__ __forceinline__ float block_reduce_any(float v) {
  #pragma unroll
  for (int o = 32; o > 0; o >>= 1) v += __shfl_down(v, o, 64);
  __shared__ float red[16];
  int lane = threadIdx.x & 63, wid = threadIdx.x >> 6;
  __syncthreads();
  if (lane == 0) red[wid] = v;
  __syncthreads();
  float r = 0.f;
  if (threadIdx.x == 0) {
    int nw = blockDim.x >> 6;
    for (int i = 0; i < nw; ++i) r += red[i];
  }
  return r;
}

// block reduce using caller-provided LDS scratch (>=4 floats) — for kernels
// whose LDS budget is exact (no room for a static red[]). 256-thread blocks.
__device__ __forceinline__ float block_reduce_scratch(float v, float* scratch) {
  #pragma unroll
  for (int o = 32; o > 0; o >>= 1) v += __shfl_down(v, o, 64);
  int lane = threadIdx.x & 63, wid = threadIdx.x >> 6;
  __syncthreads();
  if (lane == 0) scratch[wid] = v;
  __syncthreads();
  float r = 0.f;
  if (threadIdx.x == 0) {
    #pragma unroll
    for (int i = 0; i < 4; ++i) r += scratch[i];
  }
  return r;
}

// ---- radix-4 FFT core butterfly (sign = -1 fwd, +1 inv) ----
__device__ __forceinline__ void r4_bfly(float2& x0, float2& x1, float2& x2, float2& x3,
                                        float c1, float s1n, float c2, float s2n, float sign) {
  float t1x = x1.x * c1 - x1.y * s1n, t1y = x1.x * s1n + x1.y * c1;
  float y0x = x0.x + t1x, y0y = x0.y + t1y;
  float y1x = x0.x - t1x, y1y = x0.y - t1y;
  float t3x = x3.x * c1 - x3.y * s1n, t3y = x3.x * s1n + x3.y * c1;
  float y2x = x2.x + t3x, y2y = x2.y + t3y;
  float y3x = x2.x - t3x, y3y = x2.y - t3y;
  float t2x = y2x * c2 - y2y * s2n, t2y = y2x * s2n + y2y * c2;
  float ux = y3x * c2 - y3y * s2n, uy = y3x * s2n + y3y * c2;
  float t4x = -sign * uy, t4y = sign * ux;   // rotate by sign*i (fwd: -i)
  x0 = make_float2(y0x + t2x, y0y + t2y);
  x2 = make_float2(y0x - t2x, y0y - t2y);
  x1 = make_float2(y1x + t4x, y1y + t4y);
  x3 = make_float2(y1x - t4x, y1y - t4y);
}

// radix-4 FFT, 512 pts x 8 rows, 256 threads, XOR-swizzled UNPADDED rows.
__device__ __forceinline__ void fft512_r4_fwd_rows_swz(float2 (*s)[512], int lt) {
  #pragma unroll
  for (int pass = 0; pass < 4; ++pass) {
    const int sh = 2 * pass;
    const int h = 1 << sh;
    int p = lt & 127;
    int rbase = (lt >> 7) << 2;
    int j = p & (h - 1);
    int g = p >> sh;
    int base = (g << (sh + 2)) + j;
    int i0 = SWZ(base), i1 = SWZ(base + h), i2 = SWZ(base + 2 * h), i3 = SWZ(base + 3 * h);
    float ang1 = -PI_F * (float)j / (float)h;
    float s1n, c1; __sincosf(ang1, &s1n, &c1);
    float s2n, c2; __sincosf(0.5f * ang1, &s2n, &c2);
    #pragma unroll
    for (int rr = 0; rr < 4; ++rr) {
      int r = rbase + rr;
      float2 x0 = s[r][i0], x1 = s[r][i1], x2 = s[r][i2], x3 = s[r][i3];
      r4_bfly(x0, x1, x2, x3, c1, s1n, c2, s2n, -1.f);
      s[r][i0] = x0; s[r][i1] = x1; s[r][i2] = x2; s[r][i3] = x3;
    }
    __syncthreads();
  }
  {
    int p = lt;
    int i1 = SWZ(p), i2 = SWZ(p + 256);
    float ang = -PI_F * (float)p * (1.f / 256.f);
    float sn, cs; __sincosf(ang, &sn, &cs);
    #pragma unroll
    for (int r = 0; r < 8; ++r) {
      float2 a = s[r][i1], b = s[r][i2];
      float tr = b.x * cs - b.y * sn;
      float ti = b.x * sn + b.y * cs;
      s[r][i1] = make_float2(a.x + tr, a.y + ti);
      s[r][i2] = make_float2(a.x - tr, a.y - ti);
    }
    __syncthreads();
  }
}

// radix-4 FFT, 512 pts x 4 rows (packed real pairs), 256 threads, padded.
__device__ __forceinline__ void fft512_r4_fwd_rows4(float2 (*s)[RSW], int tid) {
  #pragma unroll
  for (int pass = 0; pass < 4; ++pass) {
    const int sh = 2 * pass;
    const int h = 1 << sh;
    int p = tid & 127;
    int rbase = (tid >> 7) << 1;
    int j = p & (h - 1);
    int g = p >> sh;
    int base = (g << (sh + 2)) + j;
    int i0 = PHY(base), i1 = PHY(base + h), i2 = PHY(base + 2 * h), i3 = PHY(base + 3 * h);
    float ang1 = -PI_F * (float)j / (float)h;
    float s1n, c1; __sincosf(ang1, &s1n, &c1);
    float s2n, c2; __sincosf(0.5f * ang1, &s2n, &c2);
    #pragma unroll
    for (int rr = 0; rr < 2; ++rr) {
      int r = rbase + rr;
      float2 x0 = s[r][i0], x1 = s[r][i1], x2 = s[r][i2], x3 = s[r][i3];
      r4_bfly(x0, x1, x2, x3, c1, s1n, c2, s2n, -1.f);
      s[r][i0] = x0; s[r][i1] = x1; s[r][i2] = x2; s[r][i3] = x3;
    }
    __syncthreads();
  }
  {
    int p = tid;
    int i1 = PHY(p), i2 = PHY(p + 256);
    float ang = -PI_F * (float)p * (1.f / 256.f);
    float sn, cs; __sincosf(ang, &sn, &cs);
    #pragma unroll
    for (int r = 0; r < 4; ++r) {
      float2 a = s[r][i1], b = s[r][i2];
      float tr = b.x * cs - b.y * sn;
      float ti = b.x * sn + b.y * cs;
      s[r][i1] = make_float2(a.x + tr, a.y + ti);
      s[r][i2] = make_float2(a.x - tr, a.y - ti);
    }
    __syncthreads();
  }
}

// radix-4 FFT, single 512-pt row, 256 threads, padded, sign-param.
__device__ __forceinline__ void fft512_r4_row(float2* s, int tid, float sign) {
  #pragma unroll
  for (int pass = 0; pass < 4; ++pass) {
    const int sh = 2 * pass;
    const int h = 1 << sh;
    if (tid < 128) {
      int j = tid & (h - 1);
      int g = tid >> sh;
      int base = (g << (sh + 2)) + j;
      int i0 = PHY(base), i1 = PHY(base + h), i2 = PHY(base + 2 * h), i3 = PHY(base + 3 * h);
      float ang1 = sign * PI_F * (float)j / (float)h;
      float s1n, c1; __sincosf(ang1, &s1n, &c1);
      float s2n, c2; __sincosf(0.5f * ang1, &s2n, &c2);
      float2 x0 = s[i0], x1 = s[i1], x2 = s[i2], x3 = s[i3];
      r4_bfly(x0, x1, x2, x3, c1, s1n, c2, s2n, sign);
      s[i0] = x0; s[i1] = x1; s[i2] = x2; s[i3] = x3;
    }
    __syncthreads();
  }
  {
    int i1 = PHY(tid), i2 = PHY(tid + 256);
    float ang = sign * PI_F * (float)tid * (1.f / 256.f);
    float sn, cs; __sincosf(ang, &sn, &cs);
    float2 a = s[i1], b = s[i2];
    float tr = b.x * cs - b.y * sn;
    float ti = b.x * sn + b.y * cs;
    s[i1] = make_float2(a.x + tr, a.y + ti);
    s[i2] = make_float2(a.x - tr, a.y - ti);
    __syncthreads();
  }
}

// acc layout in workspace (floats): 3 quantity groups x 16 slots x 16-float
// (64B) stride — atomics spread over 16 cache lines per group (R9 lesson:
// same-line atomics serialize ~10ns each at the coherent point).
#define ACC_G(g, slot) ((g) * 256 + ((slot) & 15) * 16)

// ---------------- K_front: FUSED {2x MLP tile | fwdT} -----------------------
// R3-verified. DO NOT retile the 128-thread MLP schedule (prior session
// R10/R11/R15 regressed — incl. 16-row wbuf); DO NOT spread the sos fill
// into fwdT blocks (R7 regressed); NO cooperative launch (R4-R6).
__global__ __launch_bounds__(256) void k_front(
    const float* __restrict__ W1, const float* __restrict__ b1,
    const float* __restrict__ W2, const float* __restrict__ b2,
    const float* __restrict__ W3, const float* __restrict__ b3,
    const float* __restrict__ W4v, const float* __restrict__ b4,
    const float* __restrict__ mgrid, const int* __restrict__ mask_idx,
    const float* __restrict__ mask, int M, int nMlpB,
    float* __restrict__ sos, float* __restrict__ acc,
    const float* __restrict__ y_img, float2* __restrict__ bufA) {
  __shared__ char raw[43008];   // MLP: 33792 hbuf + 8448 wbuf + 512 xy = 42752; fwdT: 18432
  int bid = blockIdx.x;
  int tid = threadIdx.x;
  if (bid < nMlpB) {
    // ================= two MLP tiles (64 points) =================
    float (*hbuf)[MLP_P][132] = (float (*)[MLP_P][132])raw;          // [2][32][132]
    float (*wbuf)[8][132]     = (float (*)[8][132])(raw + 33792);    // [2][8][132]
    float (*xy2)[2]           = (float (*)[2])(raw + 33792 + 8448);  // [64][2]
    int half = tid >> 7, lt = tid & 127;
    int base = bid * (2 * MLP_P) + half * MLP_P;
    if (lt < MLP_P * 2) {
      int p = lt >> 1, c = lt & 1;
      float v = 0.f;
      if (base + p < M) v = mgrid[(base + p) * 2 + c];
      xy2[half * MLP_P + p][c] = v;
    }
    if (bid == 0) {
      for (int e = tid; e < 768; e += 256) acc[e] = 0.f;
    }
    for (int slab = bid; slab < 1024; slab += nMlpB) {
      int t = slab * 256 + tid;
      if (mask[t] == 0.f) sos[t] = 1499.363f;
    }
    __syncthreads();
    for (int e = lt; e < MLP_P * 128; e += 128) {
      int p = e >> 7, j = e & 127;
      hbuf[half][p][j] = __sinf(30.f * (xy2[half * MLP_P + p][0] * W1[j] +
                                        xy2[half * MLP_P + p][1] * W1[128 + j] + b1[j]));
    }
    __syncthreads();

    int jg = lt & 15, pg = lt >> 4;
    int jA = jg * 4, jB = 64 + jg * 4;
    int p0 = pg * 4;
    int wr = tid >> 4, wc = (tid & 15) << 3;   // wbuf writer coords, valid for tid<128
    #pragma unroll
    for (int layer = 0; layer < 2; ++layer) {
      const float* Wg = layer ? W3 : W2;
      const float* bb = layer ? b3 : b2;
      float acr[4][8];
      #pragma unroll
      for (int i = 0; i < 4; ++i)
        #pragma unroll
        for (int j = 0; j < 8; ++j) acr[i][j] = 0.f;

      float4 pre1, pre2;
      if (tid < 128) {
        pre1 = *(const float4*)&Wg[wr * 128 + wc];
        pre2 = *(const float4*)&Wg[wr * 128 + wc + 4];
      }
      for (int c = 0; c < 16; ++c) {
        if (tid < 128) {
          *(float4*)&wbuf[c & 1][wr][wc] = pre1;
          *(float4*)&wbuf[c & 1][wr][wc + 4] = pre2;
        }
        __syncthreads();
        if (tid < 128 && c < 15) {
          pre1 = *(const float4*)&Wg[((c + 1) * 8 + wr) * 128 + wc];
          pre2 = *(const float4*)&Wg[((c + 1) * 8 + wr) * 128 + wc + 4];
        }
        int k0 = c * 8;
        float hreg[4][8];
        #pragma unroll
        for (int i = 0; i < 4; ++i) {
          float4 ha = *(const float4*)&hbuf[half][p0 + i][k0];
          float4 hb = *(const float4*)&hbuf[half][p0 + i][k0 + 4];
          hreg[i][0] = ha.x; hreg[i][1] = ha.y; hreg[i][2] = ha.z; hreg[i][3] = ha.w;
          hreg[i][4] = hb.x; hreg[i][5] = hb.y; hreg[i][6] = hb.z; hreg[i][7] = hb.w;
        }
        #pragma unroll
        for (int kk = 0; kk < 8; ++kk) {
          float4 wa = *(const float4*)&wbuf[c & 1][kk][jA];
          float4 wb = *(const float4*)&wbuf[c & 1][kk][jB];
          float w8[8] = {wa.x, wa.y, wa.z, wa.w, wb.x, wb.y, wb.z, wb.w};
          #pragma unroll
          for (int i = 0; i < 4; ++i) {
            float hv = hreg[i][kk];
            #pragma unroll
            for (int j = 0; j < 8; ++j) acr[i][j] += hv * w8[j];
          }
        }
      }
      float breg[8];
      #pragma unroll
      for (int j = 0; j < 4; ++j) { breg[j] = bb[jA + j]; breg[4 + j] = bb[jB + j]; }
      __syncthreads();
      #pragma unroll
      for (int i = 0; i < 4; ++i) {
        float o[8];
        #pragma unroll
        for (int j = 0; j < 8; ++j) o[j] = __sinf(30.f * (acr[i][j] + breg[j]));
        *(float4*)&hbuf[half][p0 + i][jA] = make_float4(o[0], o[1], o[2], o[3]);
        *(float4*)&hbuf[half][p0 + i][jB] = make_float4(o[4], o[5], o[6], o[7]);
      }
      __syncthreads();
    }
    {
      int p = lt >> 2, q = lt & 3;
      float s = 0.f;
      #pragma unroll
      for (int k = 0; k < 32; k += 4) {
        float4 h4 = *(const float4*)&hbuf[half][p][q * 32 + k];
        float4 w4 = *(const float4*)&W4v[q * 32 + k];
        s += h4.x * w4.x + h4.y * w4.y + h4.z * w4.z + h4.w * w4.w;
      }
      s += __shfl_down(s, 1, 64);
      s += __shfl_down(s, 2, 64);
      if (q == 0 && base + p < M)
        sos[mask_idx[base + p]] = (s + b4[0]) * 170.f + 1550.f;
    }
  } else {
    // ================= fwdT: real-pair packed v-axis FFT, Hermitian store ====
    float2 (*s)[RSW] = (float2 (*)[RSW])raw;   // [4][RSW]
    int fb = bid - nMlpB;
    int rt = fb & 31;
    int d = fb >> 5;
    const float INV2S2 = (float)(0.6931471805599453 / 1406.25);
    for (int e = tid; e < 2048; e += 256) {
      int i = e >> 8, c = e & 255;
      int r = rt * 8 + i;
      float axr = (float)r - 127.5f;
      float axc = (float)c - 127.5f;
      float g = __expf(-(axr * axr + axc * axc) * INV2S2);
      float val = y_img[((size_t)d << 16) + (r << 8) + c] * g;
      int p = i >> 1, comp = i & 1;
      ((float*)&s[p][PHY(brev9((c + 384) & 511))])[comp] = val;
      ((float*)&s[p][PHY(brev9(c + 128))])[comp] = 0.f;
    }
    __syncthreads();
    fft512_r4_fwd_rows4(s, tid);
    float2* outp = bufA + ((size_t)d << 17) + rt * 8;
    for (int e = tid; e < 2056; e += 256) {
      int i = e & 7, v = e >> 3;
      int p = i >> 1, comp = i & 1;
      float2 Zv = s[p][PHY(v)];
      float2 Zm = s[p][PHY((512 - v) & 511)];
      float2 Yv;
      if (comp == 0) Yv = make_float2(0.5f * (Zv.x + Zm.x), 0.5f * (Zv.y - Zm.y));
      else           Yv = make_float2(0.5f * (Zv.y + Zm.y), 0.5f * (Zm.x - Zv.x));
      outp[(size_t)v * 256 + i] = Yv;
    }
  }
}

// ---------------- K_side: wavefront only ----------------
__global__ __launch_bounds__(256) void k_side(
    const float* __restrict__ sos, const float* __restrict__ xq_p,
    const float* __restrict__ yq_p, const float* __restrict__ x_vec,
    const float* __restrict__ y_vec, float* __restrict__ wfs) {
  int i = blockIdx.x;
  int j = threadIdx.x;
  float xq = xq_p[0], yq = yq_p[0];
  float r = sqrtf(xq * xq + yq * yq);
  float phi = atan2f(xq, yq);
  float th = (float)((double)i * (2.0 * M_PI / 239.0));
  float sn = sinf(th - phi), cd = cosf(th - phi);
  const float R2 = 0.008f * 0.008f;
  float disc = fmaxf(R2 - (r * sn) * (r * sn), 0.f);
  float sq = sqrtf(disc);
  float l_in = sq + r * cd;
  float l_out = 2.f * sq * (cd >= 0.f ? 1.f : 0.f);
  float l = (r < 0.008f) ? l_in : l_out;
  float x0 = x_vec[0], dx = x_vec[1] - x_vec[0];
  float y0 = y_vec[0], dy = y_vec[1] - y_vec[0];
  float sinth = sinf(th), costh = cosf(th);
  float contrib = 0.f;
  if (j < NINT) {
    float sj = (float)j * (1.f / 249.f);
    int xi = (int)rintf((xq - l * sj * sinth - x0) / dx);
    int yi = (int)rintf((yq - l * sj * costh - y0) / dy);
    float sv = sos[(((-yi) & 511) << 9) + (xi & 511)];
    float f = 1.f - 1500.f / sv;
    float wgt = (j == 0 || j == NINT - 1) ? 0.5f : 1.f;
    contrib = wgt * f;
  }
  float tot = block_reduce_any(contrib);
  if (threadIdx.x == 0) wfs[i] = tot * l * (1.f / 249.f);
}

// ---------------- K3a: per-(v, 8ch-chunk) u-axis FFT + deconv partials -----
// R10 geometry (verified): 32KB LDS EXACTLY -> 5 blocks/CU = 1280 slots >=
// 1028 heavy jobs -> single round (257 prime: slots must exceed 257k). Bank
// safety via SWZ. Block-level loss reduce, ONE atomic per block, spread over
// 16 lines. Blocks [0,1024)=tvl1 light first; [1024,2052)=heavy.
__device__ __forceinline__ float interp_wf(const float* wfs, float xn) {
  const float dxg = (float)(2.0 * M_PI / 239.0);
  float t = xn / dxg;
  int f = (int)floorf(t); f = min(max(f, 0), 239);
  int c = (int)ceilf(t);  c = min(max(c, 0), 239);
  float yf = wfs[f], yc = wfs[c];
  if (c == f) return yc;
  float xgf = (float)f * dxg;
  return yf + (yc - yf) * (xn - xgf) / ((float)(c - f) * dxg);
}

__global__ __launch_bounds__(256) void k_colfft_part(
    float2* bufA,   // read 8 rows, then overlay-write partials (no restrict: aliased on purpose)
    const float* __restrict__ delays, const float* __restrict__ wfs_g,
    const float* __restrict__ sos, const float* __restrict__ mask,
    float* __restrict__ acc) {
  __shared__ float2 s[8][512];   // 32768 B EXACTLY — the kernel's only LDS
  int b = blockIdx.x;
  int tid = threadIdx.x;
  float* scratch = (float*)&s[0][0];
  if (b < 1024) {
    // ---------- tvl1 (block-level reduce via s-scratch; 2 atomics/block) ----
    int t = b * 256 + tid;
    float sv = sos[t];
    float m = mask[t];
    int i = t >> 9, j = t & 511;
    float tv = 0.f;
    if (i > 0) tv += fabsf((sv - sos[t - 512]) * m);
    if (j > 0) tv += fabsf((sv - sos[t - 1]) * m);
    float l1 = fabsf(sv - 1550.f) * m;
    float tvb = block_reduce_scratch(tv, scratch);
    float l1b = block_reduce_scratch(l1, scratch + 8);
    if (tid == 0) {
      atomicAdd(&acc[ACC_G(1, b)], tvb);
      atomicAdd(&acc[ACC_G(2, b)], l1b);
    }
    return;
  }
  int job = b - 1024;            // 0..1027
  int v = job >> 2;              // 0..256
  int h = job & 3;               // chunk of 8 channels

  // ---- stage wfs through s, preload delays to registers
  if (tid < NTH) scratch[tid] = wfs_g[tid];
  float dreg[8];
  #pragma unroll
  for (int ch = 0; ch < 8; ++ch) dreg[ch] = delays[h * 8 + ch];
  __syncthreads();

  const float inv_nd = 1.f / 0.02048f;
  const float TWO_PI = 6.28318530717958647692f;
  float fy = (float)(v < 256 ? v : v - 512) * inv_nd;
  float kkA[2];
  float2 zw[2], zwpi[2];   // exp(i kk w), exp(i kk wpi)
  #pragma unroll
  for (int uu = 0; uu < 2; ++uu) {
    int u = tid + 256 * uu;
    float fx = (float)(u < 256 ? u : u - 512) * inv_nd;
    float kk = TWO_PI * sqrtf(fx * fx + fy * fy);
    kkA[uu] = kk;
    float th = atan2f(fy, fx);
    if (th < 0.f) th += TWO_PI;
    float w = interp_wf(scratch, th);
    float thpi = th + PI_F;
    if (thpi >= TWO_PI) thpi -= TWO_PI;
    float wpi = interp_wf(scratch, thpi);
    float snw, csw; __sincosf(kk * w, &snw, &csw);
    zw[uu] = make_float2(csw, snw);
    float snp, csp; __sincosf(kk * wpi, &snp, &csp);
    zwpi[uu] = make_float2(csp, snp);
  }
  __syncthreads();   // all wfs reads done before s is overwritten

  // ---- load this chunk's 8 channels (bit-rev + ifftshifted pad placement)
  for (int e = tid; e < 2048; e += 256) {
    int ch = e >> 8, c = e & 255;
    float2 val = bufA[((size_t)(h * 8 + ch) << 17) + (size_t)v * 256 + c];
    s[ch][SWZ(brev9((c + 384) & 511))] = val;
    s[ch][SWZ(brev9(c + 128))] = make_float2(0.f, 0.f);
  }
  __syncthreads();   // also drains the global loads before overlay-writes later
  fft512_r4_fwd_rows_swz(s, tid);

  // ---- deconv accumulate over this chunk's 8 channels
  float rhsr[2] = {0.f, 0.f}, rhsi[2] = {0.f, 0.f}, lhs[2] = {0.f, 0.f};
  float sY2[2] = {0.f, 0.f}, sYH[2] = {0.f, 0.f};
  #pragma unroll
  for (int uu = 0; uu < 2; ++uu) {
    float kk = kkA[uu];
    float2 w0 = zw[uu], w1 = zwpi[uu];
    int u = SWZ(tid + 256 * uu);
    #pragma unroll
    for (int ch = 0; ch < 8; ++ch) {
      float dl = dreg[ch];
      float sd, cd2;
      __sincosf(kk * dl, &sd, &cd2);
      // H = 0.5*(conj(zd)*zw + zd*conj(zwpi)), zd = exp(i kk d)
      float t0r = cd2 * w0.x + sd * w0.y;
      float t0i = cd2 * w0.y - sd * w0.x;
      float t1r = cd2 * w1.x + sd * w1.y;
      float t1i = sd * w1.x - cd2 * w1.y;
      float Hr = 0.5f * (t0r + t1r);
      float Hi = 0.5f * (t0i + t1i);
      float2 Yv = s[ch][u];
      rhsr[uu] += Yv.x * Hr + Yv.y * Hi;
      rhsi[uu] += Yv.y * Hr - Yv.x * Hi;
      float h2 = Hr * Hr + Hi * Hi;
      float y2 = Yv.x * Yv.x + Yv.y * Yv.y;
      lhs[uu] += h2;
      sY2[uu] += y2;
      sYH[uu] += sqrtf(y2 * h2);
    }
  }

  // ---- X-independent loss term: sum kk^2 * |Y|^2 (Hermitian weight)
  float lw = (v == 0 || v == 256) ? 1.f : 2.f;
  float lsum = (kkA[0] * kkA[0] * sY2[0] + kkA[1] * kkA[1] * sY2[1]) * lw;
  float bs = block_reduce_scratch(lsum, scratch);
  if (tid == 0) atomicAdd(&acc[ACC_G(0, job)], bs);

  // ---- overlay partials into the 4 lowest consumed channel-rows:
  // float index (ch<<18) + (v<<9) + u, ch = h*8+q, q = {rhsr,rhsi,lhs,sYH}
  float* fb = (float*)bufA;
  #pragma unroll
  for (int uu = 0; uu < 2; ++uu) {
    int u = tid + 256 * uu;
    size_t base = ((size_t)v << 9) + u;
    fb[(((size_t)(h * 8 + 0)) << 18) + base] = rhsr[uu];
    fb[(((size_t)(h * 8 + 1)) << 18) + base] = rhsi[uu];
    fb[(((size_t)(h * 8 + 2)) << 18) + base] = lhs[uu];
    fb[(((size_t)(h * 8 + 3)) << 18) + base] = sYH[uu];
  }
}

// ---------------- K3b: combine partials + X + loss + u-ifft + store --------
__global__ __launch_bounds__(256) void k_colfft_fin(
    const float* __restrict__ bufP, float2* __restrict__ Xo,
    float* __restrict__ acc) {
  __shared__ float2 s[RSW];
  int v = blockIdx.x;            // 0..256
  int tid = threadIdx.x;
  const float inv_nd = 1.f / 0.02048f;
  const float TWO_PI = 6.28318530717958647692f;
  float fy = (float)(v < 256 ? v : v - 512) * inv_nd;
  float lw = (v == 0 || v == 256) ? 1.f : 2.f;
  float lsum = 0.f;
  float2 Xv[2];
  #pragma unroll
  for (int uu = 0; uu < 2; ++uu) {
    int u = tid + 256 * uu;
    float fx = (float)(u < 256 ? u : u - 512) * inv_nd;
    float kk2 = TWO_PI * TWO_PI * (fx * fx + fy * fy);
    float R = 0.f, I = 0.f, L = 0.f, YH = 0.f;
    size_t base = ((size_t)v << 9) + u;
    #pragma unroll
    for (int h = 0; h < 4; ++h) {
      R  += bufP[(((size_t)(h * 8 + 0)) << 18) + base];
      I  += bufP[(((size_t)(h * 8 + 1)) << 18) + base];
      L  += bufP[(((size_t)(h * 8 + 2)) << 18) + base];
      YH += bufP[(((size_t)(h * 8 + 3)) << 18) + base];
    }
    float Xr = R / L, Xi = I / L;
    Xv[uu] = make_float2(Xr, Xi);
    float aX = sqrtf(Xr * Xr + Xi * Xi);
    lsum += kk2 * (aX * aX * L - 2.f * aX * YH);   // |Y|^2 term added in K3a
  }
  float bs = block_reduce_any(lsum * lw);
  if (tid == 0) atomicAdd(&acc[ACC_G(0, v)], bs);

  // ---- u-axis inverse FFT of this v's X column
  s[PHY(brev9(tid))] = Xv[0];
  s[PHY(brev9(tid + 256))] = Xv[1];
  __syncthreads();
  fft512_r4_row(s, tid, +1.f);
  const float sc = 1.f / 512.f;
  float2 o0 = s[PHY(tid)], o1 = s[PHY(tid + 256)];
  o0.x *= sc; o0.y *= sc; o1.x *= sc; o1.y *= sc;
  // transposed store: Xo[u][v], Hermitian mirror for v in (0,256).
  // NOTE: this mirror makes each row Xo[u][.] conjugate-symmetric in v by
  // construction — exploited by k_final_rows' two-rows-per-IFFT packing.
  Xo[((size_t)tid << 9) + v] = o0;
  Xo[((size_t)(tid + 256) << 9) + v] = o1;
  if (v != 0 && v != 256) {
    int vm = 512 - v;
    Xo[((size_t)tid << 9) + vm] = make_float2(o0.x, -o0.y);
    Xo[((size_t)(tid + 256) << 9) + vm] = make_float2(o1.x, -o1.y);
  }
}

// ---------------- K4: final inverse row FFTs, PAIRED (2 rows/block) --------
// R14: rows of Xo are conjugate-symmetric in v (fin's mirror store), so their
// IFFTs are real. Pack rows u and u+256 as z = row_u + i*row_{u+256}: one
// complex IFFT yields row_u in .x and row_{u+256} in .y. Grid 512 -> 256.
// Contamination = the imag residue the reference discards via .real (~1e-7).
// Also finalizes loss (block 0, thread 0): sums the 16 slot-heads per group.
__global__ __launch_bounds__(256) void k_final_rows(const float2* __restrict__ buf,
                                                    float* __restrict__ xrec,
                                                    const float* __restrict__ acc,
                                                    float* __restrict__ lossout) {
  __shared__ float2 s[RSW];
  int arow = blockIdx.x;               // 0..255: handles rows arow and arow+256
  const float2* p1 = buf + ((size_t)arow << 9);
  const float2* p2 = buf + ((size_t)(arow + 256) << 9);
  int tid = threadIdx.x;
  if (arow == 0 && tid == 0) {
    float a0 = 0.f, a1 = 0.f, a2 = 0.f;
    #pragma unroll
    for (int i = 0; i < 16; ++i) {
      a0 += acc[ACC_G(0, i)];
      a1 += acc[ACC_G(1, i)];
      a2 += acc[ACC_G(2, i)];
    }
    lossout[0] = a0 * (1.f / 8388608.f) + 1e-3f * a1 + 1e-3f * (a2 * (1.f / 262144.f));
  }
  {
    float2 a1 = p1[tid],      b1 = p2[tid];
    float2 a2 = p1[tid + 256], b2 = p2[tid + 256];
    s[PHY(brev9(tid))]       = make_float2(a1.x - b1.y, a1.y + b1.x);   // z = r1 + i*r2
    s[PHY(brev9(tid + 256))] = make_float2(a2.x - b2.y, a2.y + b2.x);
  }
  __syncthreads();
  fft512_r4_row(s, tid, +1.f);
  // output rows after fftshift: row arow -> arow+256 ; row arow+256 -> arow
  int orow1 = arow + 256;
  int orow2 = arow;
  const float sc = 1.f / 512.f;
  float2 o0 = s[PHY(tid)];        // IFFT output index tid     -> col (tid+256)&511
  float2 o1 = s[PHY(tid + 256)];  // IFFT output index tid+256 -> col tid
  xrec[(orow1 << 9) + ((tid + 256) & 511)] = o0.x * sc;
  xrec[(orow1 << 9) + (tid & 511)]         = o1.x * sc;
  xrec[(orow2 << 9) + ((tid + 256) & 511)] = o0.y * sc;
  xrec[(orow2 << 9) + (tid & 511)]         = o1.y * sc;
}

// ---------------- launch ----------------
extern "C" void kernel_launch(void* const* d_in, const int* in_sizes, int n_in,
                              void* d_out, int out_size, void* d_ws, size_t ws_size,
                              hipStream_t stream) {
  const float* W1 = (const float*)d_in[0];
  const float* b1 = (const float*)d_in[1];
  const float* W2 = (const float*)d_in[2];
  const float* b2 = (const float*)d_in[3];
  const float* W3 = (const float*)d_in[4];
  const float* b3 = (const float*)d_in[5];
  const float* W4 = (const float*)d_in[6];
  const float* b4 = (const float*)d_in[7];
  const float* y_img = (const float*)d_in[8];
  const float* delays = (const float*)d_in[9];
  const float* xq = (const float*)d_in[10];
  const float* yq = (const float*)d_in[11];
  const float* mgrid = (const float*)d_in[12];
  const float* mask = (const float*)d_in[13];
  const int* mask_idx = (const int*)d_in[14];
  const float* x_vec = (const float*)d_in[15];
  const float* y_vec = (const float*)d_in[16];
  const int M = in_sizes[14];
  const int nMlpB = (M + 2 * MLP_P - 1) / (2 * MLP_P);

  float* out = (float*)d_out;
  float* xrec = out;                    // 262144
  float* sos = out + SOS_ELEMS;         // 262144
  float* loss = out + 2 * SOS_ELEMS;    // 1

  char* wsb = (char*)d_ws;
  float* acc = (float*)wsb;                                     // 768 floats (3 groups x 16 lines)
  float* wfs = (float*)(wsb + 3072);                            // 240 floats
  float2* bufA = (float2*)(wsb + 4096);                         // 32ch x 131072 c64
  float2* bufX = (float2*)(wsb + 4096 + (size_t)NDEL * 512 * 256 * sizeof(float2)); // 2 MB

  k_front<<<nMlpB + 1024, 256, 0, stream>>>(W1, b1, W2, b2, W3, b3, W4, b4,
                                            mgrid, mask_idx, mask, M, nMlpB,
                                            sos, acc, y_img, bufA);
  k_side<<<NTH, 256, 0, stream>>>(sos, xq, yq, x_vec, y_vec, wfs);
  k_colfft_part<<<1024 + 1028, 256, 0, stream>>>(bufA, delays, wfs, sos, mask, acc);
  k_colfft_fin<<<257, 256, 0, stream>>>((const float*)bufA, bufX, acc);
  k_final_rows<<<256, 256, 0, stream>>>(bufX, xrec, acc, loss);
}